// Round 11
// baseline (2002.727 us; speedup 1.0000x reference)
//
#include <hip/hip_runtime.h>

#define BN 262144

typedef short bf16x8 __attribute__((ext_vector_type(8)));
typedef float f32x4 __attribute__((ext_vector_type(4)));

#define MFMA16(a,b,c) __builtin_amdgcn_mfma_f32_16x16x32_bf16((a),(b),(c),0,0,0)

__device__ __forceinline__ unsigned short f2bf(float f) {
  union { float f; unsigned int u; } x; x.f = f;
  unsigned int u = x.u + 0x7fffu + ((x.u >> 16) & 1u);
  return (unsigned short)(u >> 16);
}
__device__ __forceinline__ float bf2f(unsigned int h) {
  union { unsigned int u; float f; } x; x.u = h << 16;
  return x.f;
}
// truncating f32->bf16 (1 VALU op); for staged intermediates
__device__ __forceinline__ unsigned short tbf(float f) {
  union { float f; unsigned int u; } x; x.f = f;
  return (unsigned short)(x.u >> 16);
}

// All weight arrays in 16x16x32 B-fragment layout (ushort units):
// elem ((ct*KS+s)*64+lane)*8+j holds B[k][n], n = ct*16+(lane&15), k = s*32+(lane>>4)*8+j
#define O_R1 0        // W1^T: B[k][n]=W1[n*64+k]   K=64  N=256 KS=2
#define O_R2 16384    // W2^T: B[k][n]=W2[n*256+k]  K=256 N=256 KS=8
#define O_R3 81920    // W3^T: B[k][n]=W3[n*256+k]  K=256 N=64  KS=8
#define O_R4 98304    // W3  : B[k][n]=W3[k*256+n]  K=64  N=256 KS=2
#define O_R5 114688   // W2  : B[k][n]=W2[k*256+n]  K=256 N=256 KS=8
#define O_R6 180224   // W1  : B[k][n]=W1[k*64+n]   K=256 N=64  KS=8
#define N_WS 196608

__global__ void invres_prep(const float* __restrict__ W1, const float* __restrict__ W2,
                            const float* __restrict__ W3, unsigned short* __restrict__ wsb) {
  int idx = blockIdx.x * 256 + threadIdx.x;
  if (idx >= N_WS) return;
  int j = idx & 7;
  int lane = (idx >> 3) & 63;
  int nn = lane & 15, kn = (lane >> 4) * 8 + j;
  float val;
  if (idx < O_R2) {                // R1, KS=2
    int g = idx >> 9; int s = g & 1; int ct = g >> 1;
    val = W1[(ct * 16 + nn) * 64 + (s * 32 + kn)];
  } else if (idx < O_R3) {         // R2, KS=8
    int g = (idx - O_R2) >> 9; int s = g & 7; int ct = g >> 3;
    val = W2[(ct * 16 + nn) * 256 + (s * 32 + kn)];
  } else if (idx < O_R4) {         // R3, KS=8
    int g = (idx - O_R3) >> 9; int s = g & 7; int ct = g >> 3;
    val = W3[(ct * 16 + nn) * 256 + (s * 32 + kn)];
  } else if (idx < O_R5) {         // R4, KS=2
    int g = (idx - O_R4) >> 9; int s = g & 1; int ct = g >> 1;
    val = W3[(s * 32 + kn) * 256 + (ct * 16 + nn)];
  } else if (idx < O_R6) {         // R5, KS=8
    int g = (idx - O_R5) >> 9; int s = g & 7; int ct = g >> 3;
    val = W2[(s * 32 + kn) * 256 + (ct * 16 + nn)];
  } else {                         // R6, KS=8
    int g = (idx - O_R6) >> 9; int s = g & 7; int ct = g >> 3;
    val = W1[(s * 32 + kn) * 64 + (ct * 16 + nn)];
  }
  wsb[idx] = f2bf(val);
}

// LDS (per block, M=64), aliased:
//  PA 64x256 bf16 swz (32K): h1 (G1 out, G2 in) then u2 (G4/G4' out, G5 in)
//  PB 64x256 bf16 swz (32K): h2 (G2 out, G3 in) then u1 (G5 out, G6 in)
//  WB 64x64  bf16 swz (8K) : w  (G6 out, G4' in)
//  LDP f32[64][4] (1K)
#define L_PB  32768
#define L_WB  65536
#define L_LDP 73728
#define L_SIZE 74752

__global__ void __launch_bounds__(512, 4)
invres_main(const float* __restrict__ y, const float* __restrict__ ldj,
            const float* __restrict__ v, const float* __restrict__ b1,
            const float* __restrict__ b2, const float* __restrict__ b3,
            const unsigned short* __restrict__ wsb, float* __restrict__ out) {
  extern __shared__ char smem[];
  char* PA = smem;
  char* PB = smem + L_PB;
  char* WB = smem + L_WB;
  float* ldp = (float*)(smem + L_LDP);

  const int tid = threadIdx.x;
  const int lane = tid & 63;
  const int wid = tid >> 6;          // 0..7
  const int l15 = lane & 15, g16 = lane >> 4;
  const int ct0 = wid * 2;           // wide: col tiles ct0, ct0+1 (32 cols)
  const int mq = (wid >> 2) * 2;     // narrow: row tiles mq, mq+1
  const int ctn = wid & 3;           // narrow: col tile (16 cols)
  const int r0 = blockIdx.x * 64;

  const bf16x8* R1 = (const bf16x8*)(wsb + O_R1);
  const bf16x8* R2 = (const bf16x8*)(wsb + O_R2);
  const bf16x8* R3 = (const bf16x8*)(wsb + O_R3);
  const bf16x8* R4 = (const bf16x8*)(wsb + O_R4);
  const bf16x8* R5 = (const bf16x8*)(wsb + O_R5);
  const bf16x8* R6 = (const bf16x8*)(wsb + O_R6);

  // A-fragment (16x16x32) from 64x256 swizzled LDS buffer
  auto ldsA = [&](const char* buf, int mm, int s) -> bf16x8 {
    int row = mm * 16 + l15;
    unsigned byte = ((unsigned)(s * 64 + g16 * 16)) ^ ((unsigned)(row & 7) << 4);
    return *(const bf16x8*)(buf + row * 512 + byte);
  };
  // D-layout truncating store into 64x256 swizzled LDS buffer (wide phases)
  auto dstoreW = [&](char* buf, int mm, int cc, int r, float val) {
    int row = mm * 16 + g16 * 4 + r;
    int col = (ct0 + cc) * 16 + l15;
    *(unsigned short*)(buf + row * 512 + (((unsigned)(col * 2)) ^ ((unsigned)(row & 7) << 4))) = tbf(val);
  };
  // global A-fragment from y/v (row-major fp32), NT
  auto gA = [&](const float* p, int mm, int s, bool elu) -> bf16x8 {
    const float* q = p + (size_t)(r0 + mm * 16 + l15) * 64 + s * 32 + g16 * 8;
    f32x4 a = __builtin_nontemporal_load((const f32x4*)q);
    f32x4 b = __builtin_nontemporal_load((const f32x4*)(q + 4));
    float xv[8] = {a[0], a[1], a[2], a[3], b[0], b[1], b[2], b[3]};
    bf16x8 f;
#pragma unroll
    for (int i = 0; i < 8; i++) {
      float x = xv[i];
      if (elu) x = x > 0.f ? x : (__expf(x) - 1.f);
      f[i] = (short)f2bf(x);
    }
    return f;
  };

  float bb1[2], bb2[2];
#pragma unroll
  for (int cc = 0; cc < 2; cc++) {
    bb1[cc] = b1[(ct0 + cc) * 16 + l15];
    bb2[cc] = b2[(ct0 + cc) * 16 + l15];
  }
  const float bb3 = b3[ctn * 16 + l15];

  unsigned d1p[16], d2p[16], d0p[4], v0p[4];
  float ldacc[8];
#pragma unroll
  for (int i = 0; i < 8; i++) ldacc[i] = 0.f;

  // ---------------- G1: h1 = elu(elu(y) @ W1^T + b1) -> PA ; d1 -> regs ----------------
  {
    f32x4 acc[4][2] = {};
#pragma unroll
    for (int s = 0; s < 2; s++) {
      bf16x8 B0 = R1[(ct0 * 2 + s) * 64 + lane];
      bf16x8 B1 = R1[((ct0 + 1) * 2 + s) * 64 + lane];
#pragma unroll
      for (int mm = 0; mm < 4; mm++) {
        bf16x8 a = gA(y, mm, s, true);
        acc[mm][0] = MFMA16(a, B0, acc[mm][0]);
        acc[mm][1] = MFMA16(a, B1, acc[mm][1]);
      }
    }
#pragma unroll
    for (int mm = 0; mm < 4; mm++)
#pragma unroll
      for (int cc = 0; cc < 2; cc++)
#pragma unroll
        for (int r = 0; r < 4; r++) {
          float a = acc[mm][cc][r] + bb1[cc];
          float e = __expf(a);
          float h = a > 0.f ? a : (e - 1.f);
          unsigned dd = f2bf(a > 0.f ? 1.f : e);
          dstoreW(PA, mm, cc, r, h);
          int idx = (mm * 2 + cc) * 2 + (r >> 1);
          d1p[idx] = (r & 1) ? (d1p[idx] | (dd << 16)) : dd;
        }
  }
  __syncthreads();

  // ---------------- G2: h2 = elu(h1 @ W2^T + b2) -> PB ; d2 -> regs ----------------
  {
    f32x4 acc[4][2] = {};
#pragma unroll 1
    for (int s = 0; s < 8; s++) {
      bf16x8 B0 = R2[(ct0 * 8 + s) * 64 + lane];
      bf16x8 B1 = R2[((ct0 + 1) * 8 + s) * 64 + lane];
#pragma unroll
      for (int mm = 0; mm < 4; mm++) {
        bf16x8 a = ldsA(PA, mm, s);
        acc[mm][0] = MFMA16(a, B0, acc[mm][0]);
        acc[mm][1] = MFMA16(a, B1, acc[mm][1]);
      }
    }
#pragma unroll
    for (int mm = 0; mm < 4; mm++)
#pragma unroll
      for (int cc = 0; cc < 2; cc++)
#pragma unroll
        for (int r = 0; r < 4; r++) {
          float a = acc[mm][cc][r] + bb2[cc];
          float e = __expf(a);
          float h = a > 0.f ? a : (e - 1.f);
          unsigned dd = f2bf(a > 0.f ? 1.f : e);
          dstoreW(PB, mm, cc, r, h);
          int idx = (mm * 2 + cc) * 2 + (r >> 1);
          d2p[idx] = (r & 1) ? (d2p[idx] | (dd << 16)) : dd;
        }
  }
  __syncthreads();

  // ---------------- G3: z = y + h2 @ W3^T + b3 ; d0, v0 ----------------
  {
    f32x4 acc[2] = {};
#pragma unroll 1
    for (int s = 0; s < 8; s++) {
      bf16x8 B = R3[(ctn * 8 + s) * 64 + lane];
      acc[0] = MFMA16(ldsA(PB, mq, s), B, acc[0]);
      acc[1] = MFMA16(ldsA(PB, mq + 1, s), B, acc[1]);
    }
#pragma unroll
    for (int q = 0; q < 2; q++)
#pragma unroll
      for (int r = 0; r < 4; r++) {
        int row = r0 + (mq + q) * 16 + g16 * 4 + r;
        int col = ctn * 16 + l15;
        size_t off = (size_t)row * 64 + col;
        float yv = __builtin_nontemporal_load(y + off);
        __builtin_nontemporal_store(yv + acc[q][r] + bb3, out + off);
        unsigned dd = f2bf(yv > 0.f ? 1.f : __expf(yv));
        unsigned vv = f2bf(__builtin_nontemporal_load(v + off));
        int idx = q * 2 + (r >> 1);
        d0p[idx] = (r & 1) ? (d0p[idx] | (dd << 16)) : dd;
        v0p[idx] = (r & 1) ? (v0p[idx] | (vv << 16)) : vv;
      }
  }

  // ---------------- G4 (k=1): u2 = (v0 @ W3) * d2 -> PA ----------------
  {
    f32x4 acc[4][2] = {};
#pragma unroll
    for (int s = 0; s < 2; s++) {
      bf16x8 B0 = R4[(ct0 * 2 + s) * 64 + lane];
      bf16x8 B1 = R4[((ct0 + 1) * 2 + s) * 64 + lane];
#pragma unroll
      for (int mm = 0; mm < 4; mm++) {
        bf16x8 a = gA(v, mm, s, false);
        acc[mm][0] = MFMA16(a, B0, acc[mm][0]);
        acc[mm][1] = MFMA16(a, B1, acc[mm][1]);
      }
    }
#pragma unroll
    for (int mm = 0; mm < 4; mm++)
#pragma unroll
      for (int cc = 0; cc < 2; cc++)
#pragma unroll
        for (int r = 0; r < 4; r++) {
          int idx = (mm * 2 + cc) * 2 + (r >> 1);
          float u = acc[mm][cc][r] * bf2f((d2p[idx] >> ((r & 1) * 16)) & 0xffffu);
          dstoreW(PA, mm, cc, r, u);
        }
  }
  __syncthreads();

  // ---------------- backward iterations ----------------
  for (int k = 1; k <= 8; ++k) {
    // G5: u1 = (u2 @ W2) * d1 -> PB
    {
      f32x4 acc[4][2] = {};
#pragma unroll 1
      for (int s = 0; s < 8; s++) {
        bf16x8 B0 = R5[(ct0 * 8 + s) * 64 + lane];
        bf16x8 B1 = R5[((ct0 + 1) * 8 + s) * 64 + lane];
#pragma unroll
        for (int mm = 0; mm < 4; mm++) {
          bf16x8 a = ldsA(PA, mm, s);
          acc[mm][0] = MFMA16(a, B0, acc[mm][0]);
          acc[mm][1] = MFMA16(a, B1, acc[mm][1]);
        }
      }
#pragma unroll
      for (int mm = 0; mm < 4; mm++)
#pragma unroll
        for (int cc = 0; cc < 2; cc++)
#pragma unroll
          for (int r = 0; r < 4; r++) {
            int idx = (mm * 2 + cc) * 2 + (r >> 1);
            float u = acc[mm][cc][r] * bf2f((d1p[idx] >> ((r & 1) * 16)) & 0xffffu);
            dstoreW(PB, mm, cc, r, u);
          }
    }
    __syncthreads();

    // G6: w' = (u1 @ W1) * d0 ; log-det ; w' -> WB
    {
      float coef = (k & 1) ? (1.f / (float)k) : (-1.f / (float)k);
      f32x4 acc[2] = {};
#pragma unroll 1
      for (int s = 0; s < 8; s++) {
        bf16x8 B = R6[(ctn * 8 + s) * 64 + lane];
        acc[0] = MFMA16(ldsA(PB, mq, s), B, acc[0]);
        acc[1] = MFMA16(ldsA(PB, mq + 1, s), B, acc[1]);
      }
#pragma unroll
      for (int q = 0; q < 2; q++)
#pragma unroll
        for (int r = 0; r < 4; r++) {
          int idx = q * 2 + (r >> 1);
          float wv = acc[q][r] * bf2f((d0p[idx] >> ((r & 1) * 16)) & 0xffffu);
          ldacc[q * 4 + r] += coef * wv * bf2f((v0p[idx] >> ((r & 1) * 16)) & 0xffffu);
          if (k < 8) {
            int row = (mq + q) * 16 + g16 * 4 + r;
            int col = ctn * 16 + l15;
            *(unsigned short*)(WB + row * 128 + (((unsigned)(col * 2)) ^ ((unsigned)(row & 7) << 4))) = tbf(wv);
          }
        }
    }
    if (k < 8) {
      __syncthreads();
      // G4': u2 = (w' @ W3) * d2 -> PA
      f32x4 acc[4][2] = {};
#pragma unroll
      for (int s = 0; s < 2; s++) {
        bf16x8 B0 = R4[(ct0 * 2 + s) * 64 + lane];
        bf16x8 B1 = R4[((ct0 + 1) * 2 + s) * 64 + lane];
#pragma unroll
        for (int mm = 0; mm < 4; mm++) {
          int row = mm * 16 + l15;
          unsigned byte = ((unsigned)(s * 64 + g16 * 16)) ^ ((unsigned)(row & 7) << 4);
          bf16x8 a = *(const bf16x8*)(WB + row * 128 + byte);
          acc[mm][0] = MFMA16(a, B0, acc[mm][0]);
          acc[mm][1] = MFMA16(a, B1, acc[mm][1]);
        }
      }
#pragma unroll
      for (int mm = 0; mm < 4; mm++)
#pragma unroll
        for (int cc = 0; cc < 2; cc++)
#pragma unroll
          for (int r = 0; r < 4; r++) {
            int idx = (mm * 2 + cc) * 2 + (r >> 1);
            float u = acc[mm][cc][r] * bf2f((d2p[idx] >> ((r & 1) * 16)) & 0xffffu);
            dstoreW(PA, mm, cc, r, u);
          }
      __syncthreads();
    }
  }

  // ---------------- log-det epilogue ----------------
#pragma unroll
  for (int i = 0; i < 8; i++) {
    float s = ldacc[i];
    s += __shfl_xor(s, 1);
    s += __shfl_xor(s, 2);
    s += __shfl_xor(s, 4);
    s += __shfl_xor(s, 8);
    ldacc[i] = s;
  }
  if (l15 == 0) {
#pragma unroll
    for (int q = 0; q < 2; q++)
#pragma unroll
      for (int r = 0; r < 4; r++) {
        int row = (mq + q) * 16 + g16 * 4 + r;
        ldp[row * 4 + ctn] = ldacc[q * 4 + r];
      }
  }
  __syncthreads();
  if (tid < 64) {
    float s = ldp[tid * 4] + ldp[tid * 4 + 1] + ldp[tid * 4 + 2] + ldp[tid * 4 + 3];
    int gb = r0 + tid;
    __builtin_nontemporal_store(ldj[gb] + s, out + (size_t)BN * 64 + gb);
  }
}

extern "C" void kernel_launch(void* const* d_in, const int* in_sizes, int n_in,
                              void* d_out, int out_size, void* d_ws, size_t ws_size,
                              hipStream_t stream) {
  const float* y   = (const float*)d_in[0];
  const float* ldj = (const float*)d_in[1];
  const float* v   = (const float*)d_in[2];
  const float* W1  = (const float*)d_in[3];
  const float* b1  = (const float*)d_in[4];
  const float* W2  = (const float*)d_in[5];
  const float* b2  = (const float*)d_in[6];
  const float* W3  = (const float*)d_in[7];
  const float* b3  = (const float*)d_in[8];
  unsigned short* wsb = (unsigned short*)d_ws;
  float* out = (float*)d_out;

  (void)hipFuncSetAttribute(reinterpret_cast<const void*>(&invres_main),
                            hipFuncAttributeMaxDynamicSharedMemorySize, L_SIZE);

  invres_prep<<<N_WS / 256, 256, 0, stream>>>(W1, W2, W3, wsb);
  invres_main<<<BN / 64, 512, L_SIZE, stream>>>(y, ldj, v, b1, b2, b3, wsb, out);
}

// Round 12
// 851.614 us; speedup vs baseline: 2.3517x; 2.3517x over previous
//
#include <hip/hip_runtime.h>

#define BN 262144

typedef short bf16x8 __attribute__((ext_vector_type(8)));
typedef float f32x4 __attribute__((ext_vector_type(4)));

#define MFMA16(a,b,c) __builtin_amdgcn_mfma_f32_16x16x32_bf16((a),(b),(c),0,0,0)

__device__ __forceinline__ unsigned short f2bf(float f) {
  union { float f; unsigned int u; } x; x.f = f;
  unsigned int u = x.u + 0x7fffu + ((x.u >> 16) & 1u);
  return (unsigned short)(u >> 16);
}
__device__ __forceinline__ float bf2f(unsigned int h) {
  union { unsigned int u; float f; } x; x.u = h << 16;
  return x.f;
}
// truncating f32->bf16 (1 VALU op); for staged intermediates
__device__ __forceinline__ unsigned short tbf(float f) {
  union { float f; unsigned int u; } x; x.f = f;
  return (unsigned short)(x.u >> 16);
}

// All weight arrays in 16x16x32 B-fragment layout (ushort units):
// elem ((ct*KS+s)*64+lane)*8+j holds B[k][n], n = ct*16+(lane&15), k = s*32+(lane>>4)*8+j
#define O_R1 0        // W1^T: B[k][n]=W1[n*64+k]   K=64  N=256 KS=2
#define O_R2 16384    // W2^T: B[k][n]=W2[n*256+k]  K=256 N=256 KS=8
#define O_R3 81920    // W3^T: B[k][n]=W3[n*256+k]  K=256 N=64  KS=8
#define O_R4 98304    // W3  : B[k][n]=W3[k*256+n]  K=64  N=256 KS=2
#define O_R5 114688   // W2  : B[k][n]=W2[k*256+n]  K=256 N=256 KS=8
#define O_R6 180224   // W1  : B[k][n]=W1[k*64+n]   K=256 N=64  KS=8
#define N_WS 196608

__global__ void invres_prep(const float* __restrict__ W1, const float* __restrict__ W2,
                            const float* __restrict__ W3, unsigned short* __restrict__ wsb) {
  int idx = blockIdx.x * 256 + threadIdx.x;
  if (idx >= N_WS) return;
  int j = idx & 7;
  int lane = (idx >> 3) & 63;
  int nn = lane & 15, kn = (lane >> 4) * 8 + j;
  float val;
  if (idx < O_R2) {                // R1, KS=2
    int g = idx >> 9; int s = g & 1; int ct = g >> 1;
    val = W1[(ct * 16 + nn) * 64 + (s * 32 + kn)];
  } else if (idx < O_R3) {         // R2, KS=8
    int g = (idx - O_R2) >> 9; int s = g & 7; int ct = g >> 3;
    val = W2[(ct * 16 + nn) * 256 + (s * 32 + kn)];
  } else if (idx < O_R4) {         // R3, KS=8
    int g = (idx - O_R3) >> 9; int s = g & 7; int ct = g >> 3;
    val = W3[(ct * 16 + nn) * 256 + (s * 32 + kn)];
  } else if (idx < O_R5) {         // R4, KS=2
    int g = (idx - O_R4) >> 9; int s = g & 1; int ct = g >> 1;
    val = W3[(s * 32 + kn) * 256 + (ct * 16 + nn)];
  } else if (idx < O_R6) {         // R5, KS=8
    int g = (idx - O_R5) >> 9; int s = g & 7; int ct = g >> 3;
    val = W2[(s * 32 + kn) * 256 + (ct * 16 + nn)];
  } else {                         // R6, KS=8
    int g = (idx - O_R6) >> 9; int s = g & 7; int ct = g >> 3;
    val = W1[(s * 32 + kn) * 64 + (ct * 16 + nn)];
  }
  wsb[idx] = f2bf(val);
}

// LDS (per block, M=32), buffers aliased across phases:
//  PA 32x256 bf16 swz (16K): h1 (G1 out, G2 in) then u2 (G4/G4' out, G5 in)
//  PB 32x256 bf16 swz (16K): h2 (G2 out, G3 in) then u1 (G5 out, G6 in)
//  WB 32x64  bf16 swz (4K) : w  (G6 out, G4' in)
//  LDP f32[32][4] (512B)
#define L_PB  16384
#define L_WB  32768
#define L_LDP 36864
#define L_SIZE 37376

__global__ void __launch_bounds__(512, 4)
invres_main(const float* __restrict__ y, const float* __restrict__ ldj,
            const float* __restrict__ v, const float* __restrict__ b1,
            const float* __restrict__ b2, const float* __restrict__ b3,
            const unsigned short* __restrict__ wsb, float* __restrict__ out) {
  extern __shared__ char smem[];
  char* PA = smem;
  char* PB = smem + L_PB;
  char* WB = smem + L_WB;
  float* ldp = (float*)(smem + L_LDP);

  const int tid = threadIdx.x;
  const int lane = tid & 63;
  const int wid = tid >> 6;          // 0..7
  const int l15 = lane & 15, g16 = lane >> 4;
  const int ct0 = wid * 2;           // wide: col tiles ct0, ct0+1 (32 cols)
  const int mh = wid >> 2;           // narrow: row half (16 rows)
  const int ctn = wid & 3;           // narrow: col tile (16 cols)
  const int r0 = blockIdx.x * 32;

  const bf16x8* R1 = (const bf16x8*)(wsb + O_R1);
  const bf16x8* R2 = (const bf16x8*)(wsb + O_R2);
  const bf16x8* R3 = (const bf16x8*)(wsb + O_R3);
  const bf16x8* R4 = (const bf16x8*)(wsb + O_R4);
  const bf16x8* R5 = (const bf16x8*)(wsb + O_R5);
  const bf16x8* R6 = (const bf16x8*)(wsb + O_R6);

  // A-fragment (16x16x32) from 32x256 swizzled LDS buffer
  auto ldsA = [&](const char* buf, int mm, int s) -> bf16x8 {
    int row = mm * 16 + l15;
    unsigned byte = ((unsigned)(s * 64 + g16 * 16)) ^ ((unsigned)(row & 7) << 4);
    return *(const bf16x8*)(buf + row * 512 + byte);
  };
  // D-layout truncating store into 32x256 swizzled LDS buffer (wide phases)
  auto dstoreW = [&](char* buf, int mm, int cc, int r, float val) {
    int row = mm * 16 + g16 * 4 + r;
    int col = (ct0 + cc) * 16 + l15;
    *(unsigned short*)(buf + row * 512 + (((unsigned)(col * 2)) ^ ((unsigned)(row & 7) << 4))) = tbf(val);
  };
  // global A-fragment from y/v (row-major fp32), NT
  auto gA = [&](const float* p, int mm, int s, bool elu) -> bf16x8 {
    const float* q = p + (size_t)(r0 + mm * 16 + l15) * 64 + s * 32 + g16 * 8;
    f32x4 a = __builtin_nontemporal_load((const f32x4*)q);
    f32x4 b = __builtin_nontemporal_load((const f32x4*)(q + 4));
    float xv[8] = {a[0], a[1], a[2], a[3], b[0], b[1], b[2], b[3]};
    bf16x8 f;
#pragma unroll
    for (int i = 0; i < 8; i++) {
      float x = xv[i];
      if (elu) x = x > 0.f ? x : (__expf(x) - 1.f);
      f[i] = (short)f2bf(x);
    }
    return f;
  };

  float bb1[2], bb2[2];
#pragma unroll
  for (int cc = 0; cc < 2; cc++) {
    bb1[cc] = b1[(ct0 + cc) * 16 + l15];
    bb2[cc] = b2[(ct0 + cc) * 16 + l15];
  }
  const float bb3 = b3[ctn * 16 + l15];

  unsigned d1p[8], d2p[8], d0p[2], v0p[2];
  float ldacc[4] = {0.f, 0.f, 0.f, 0.f};

  // ---------------- G1: h1 = elu(elu(y) @ W1^T + b1) -> PA ; d1 -> regs ----------------
  {
    f32x4 acc[2][2] = {};
#pragma unroll
    for (int s = 0; s < 2; s++) {
      bf16x8 a0 = gA(y, 0, s, true);
      bf16x8 a1 = gA(y, 1, s, true);
#pragma unroll
      for (int cc = 0; cc < 2; cc++) {
        bf16x8 B = R1[((ct0 + cc) * 2 + s) * 64 + lane];
        acc[0][cc] = MFMA16(a0, B, acc[0][cc]);
        acc[1][cc] = MFMA16(a1, B, acc[1][cc]);
      }
    }
#pragma unroll
    for (int mm = 0; mm < 2; mm++)
#pragma unroll
      for (int cc = 0; cc < 2; cc++)
#pragma unroll
        for (int r = 0; r < 4; r++) {
          float a = acc[mm][cc][r] + bb1[cc];
          float e = __expf(a);
          float h = a > 0.f ? a : (e - 1.f);
          unsigned dd = f2bf(a > 0.f ? 1.f : e);
          dstoreW(PA, mm, cc, r, h);
          int idx = (mm * 2 + cc) * 2 + (r >> 1);
          d1p[idx] = (r & 1) ? (d1p[idx] | (dd << 16)) : dd;
        }
  }
  __syncthreads();

  // ---------------- G2: h2 = elu(h1 @ W2^T + b2) -> PB ; d2 -> regs ----------------
  {
    f32x4 acc[2][2] = {};
    bf16x8 B0 = R2[(ct0 * 8) * 64 + lane];
    bf16x8 B1 = R2[((ct0 + 1) * 8) * 64 + lane];
#pragma unroll 1
    for (int s = 0; s < 8; s++) {
      bf16x8 cB0 = B0, cB1 = B1;
      int sn = s + 1 < 8 ? s + 1 : 7;
      B0 = R2[(ct0 * 8 + sn) * 64 + lane];
      B1 = R2[((ct0 + 1) * 8 + sn) * 64 + lane];
      bf16x8 a0 = ldsA(PA, 0, s);
      bf16x8 a1 = ldsA(PA, 1, s);
      acc[0][0] = MFMA16(a0, cB0, acc[0][0]);
      acc[0][1] = MFMA16(a0, cB1, acc[0][1]);
      acc[1][0] = MFMA16(a1, cB0, acc[1][0]);
      acc[1][1] = MFMA16(a1, cB1, acc[1][1]);
    }
#pragma unroll
    for (int mm = 0; mm < 2; mm++)
#pragma unroll
      for (int cc = 0; cc < 2; cc++)
#pragma unroll
        for (int r = 0; r < 4; r++) {
          float a = acc[mm][cc][r] + bb2[cc];
          float e = __expf(a);
          float h = a > 0.f ? a : (e - 1.f);
          unsigned dd = f2bf(a > 0.f ? 1.f : e);
          dstoreW(PB, mm, cc, r, h);
          int idx = (mm * 2 + cc) * 2 + (r >> 1);
          d2p[idx] = (r & 1) ? (d2p[idx] | (dd << 16)) : dd;
        }
  }
  __syncthreads();

  // ---------------- G3: z = y + h2 @ W3^T + b3 ; d0, v0 ----------------
  {
    f32x4 acc0 = {}, acc1 = {};
    bf16x8 Ba = R3[(ctn * 8 + 0) * 64 + lane];
    bf16x8 Bb = R3[(ctn * 8 + 1) * 64 + lane];
#pragma unroll 1
    for (int s = 0; s < 8; s += 2) {
      bf16x8 ca = Ba, cb = Bb;
      int sn = s + 2 < 8 ? s + 2 : 0;
      Ba = R3[(ctn * 8 + sn) * 64 + lane];
      Bb = R3[(ctn * 8 + sn + 1) * 64 + lane];
      acc0 = MFMA16(ldsA(PB, mh, s), ca, acc0);
      acc1 = MFMA16(ldsA(PB, mh, s + 1), cb, acc1);
    }
#pragma unroll
    for (int r = 0; r < 4; r++) {
      float av = acc0[r] + acc1[r];
      int row = r0 + mh * 16 + g16 * 4 + r;
      int col = ctn * 16 + l15;
      size_t off = (size_t)row * 64 + col;
      float yv = __builtin_nontemporal_load(y + off);
      __builtin_nontemporal_store(yv + av + bb3, out + off);
      unsigned dd = f2bf(yv > 0.f ? 1.f : __expf(yv));
      unsigned vv = f2bf(__builtin_nontemporal_load(v + off));
      d0p[r >> 1] = (r & 1) ? (d0p[r >> 1] | (dd << 16)) : dd;
      v0p[r >> 1] = (r & 1) ? (v0p[r >> 1] | (vv << 16)) : vv;
    }
  }

  // ---------------- G4 (k=1): u2 = (v0 @ W3) * d2 -> PA ----------------
  {
    f32x4 acc[2][2] = {};
#pragma unroll
    for (int s = 0; s < 2; s++) {
      bf16x8 a0 = gA(v, 0, s, false);
      bf16x8 a1 = gA(v, 1, s, false);
#pragma unroll
      for (int cc = 0; cc < 2; cc++) {
        bf16x8 B = R4[((ct0 + cc) * 2 + s) * 64 + lane];
        acc[0][cc] = MFMA16(a0, B, acc[0][cc]);
        acc[1][cc] = MFMA16(a1, B, acc[1][cc]);
      }
    }
#pragma unroll
    for (int mm = 0; mm < 2; mm++)
#pragma unroll
      for (int cc = 0; cc < 2; cc++)
#pragma unroll
        for (int r = 0; r < 4; r++) {
          int idx = (mm * 2 + cc) * 2 + (r >> 1);
          float u = acc[mm][cc][r] * bf2f((d2p[idx] >> ((r & 1) * 16)) & 0xffffu);
          dstoreW(PA, mm, cc, r, u);
        }
  }
  __syncthreads();

  // ---------------- backward iterations ----------------
  for (int k = 1; k <= 8; ++k) {
    // G5: u1 = (u2 @ W2) * d1 -> PB
    {
      f32x4 acc[2][2] = {};
      bf16x8 B0 = R5[(ct0 * 8) * 64 + lane];
      bf16x8 B1 = R5[((ct0 + 1) * 8) * 64 + lane];
#pragma unroll 1
      for (int s = 0; s < 8; s++) {
        bf16x8 cB0 = B0, cB1 = B1;
        int sn = s + 1 < 8 ? s + 1 : 7;
        B0 = R5[(ct0 * 8 + sn) * 64 + lane];
        B1 = R5[((ct0 + 1) * 8 + sn) * 64 + lane];
        bf16x8 a0 = ldsA(PA, 0, s);
        bf16x8 a1 = ldsA(PA, 1, s);
        acc[0][0] = MFMA16(a0, cB0, acc[0][0]);
        acc[0][1] = MFMA16(a0, cB1, acc[0][1]);
        acc[1][0] = MFMA16(a1, cB0, acc[1][0]);
        acc[1][1] = MFMA16(a1, cB1, acc[1][1]);
      }
#pragma unroll
      for (int mm = 0; mm < 2; mm++)
#pragma unroll
        for (int cc = 0; cc < 2; cc++)
#pragma unroll
          for (int r = 0; r < 4; r++) {
            int idx = (mm * 2 + cc) * 2 + (r >> 1);
            float u = acc[mm][cc][r] * bf2f((d1p[idx] >> ((r & 1) * 16)) & 0xffffu);
            dstoreW(PB, mm, cc, r, u);
          }
    }
    __syncthreads();

    // G6: w' = (u1 @ W1) * d0 ; log-det ; w' -> WB
    {
      float coef = (k & 1) ? (1.f / (float)k) : (-1.f / (float)k);
      f32x4 acc0 = {}, acc1 = {};
      bf16x8 Ba = R6[(ctn * 8 + 0) * 64 + lane];
      bf16x8 Bb = R6[(ctn * 8 + 1) * 64 + lane];
#pragma unroll 1
      for (int s = 0; s < 8; s += 2) {
        bf16x8 ca = Ba, cb = Bb;
        int sn = s + 2 < 8 ? s + 2 : 0;
        Ba = R6[(ctn * 8 + sn) * 64 + lane];
        Bb = R6[(ctn * 8 + sn + 1) * 64 + lane];
        acc0 = MFMA16(ldsA(PB, mh, s), ca, acc0);
        acc1 = MFMA16(ldsA(PB, mh, s + 1), cb, acc1);
      }
#pragma unroll
      for (int r = 0; r < 4; r++) {
        float wv = (acc0[r] + acc1[r]) * bf2f((d0p[r >> 1] >> ((r & 1) * 16)) & 0xffffu);
        ldacc[r] += coef * wv * bf2f((v0p[r >> 1] >> ((r & 1) * 16)) & 0xffffu);
        if (k < 8) {
          int row = mh * 16 + g16 * 4 + r;
          int col = ctn * 16 + l15;
          *(unsigned short*)(WB + row * 128 + (((unsigned)(col * 2)) ^ ((unsigned)(row & 7) << 4))) = tbf(wv);
        }
      }
    }
    if (k < 8) {
      __syncthreads();
      // G4': u2 = (w' @ W3) * d2 -> PA
      f32x4 acc[2][2] = {};
#pragma unroll
      for (int s = 0; s < 2; s++) {
        bf16x8 a0, a1;
#pragma unroll
        for (int mm = 0; mm < 2; mm++) {
          int row = mm * 16 + l15;
          unsigned byte = ((unsigned)(s * 64 + g16 * 16)) ^ ((unsigned)(row & 7) << 4);
          bf16x8 a = *(const bf16x8*)(WB + row * 128 + byte);
          if (mm == 0) a0 = a; else a1 = a;
        }
#pragma unroll
        for (int cc = 0; cc < 2; cc++) {
          bf16x8 B = R4[((ct0 + cc) * 2 + s) * 64 + lane];
          acc[0][cc] = MFMA16(a0, B, acc[0][cc]);
          acc[1][cc] = MFMA16(a1, B, acc[1][cc]);
        }
      }
#pragma unroll
      for (int mm = 0; mm < 2; mm++)
#pragma unroll
        for (int cc = 0; cc < 2; cc++)
#pragma unroll
          for (int r = 0; r < 4; r++) {
            int idx = (mm * 2 + cc) * 2 + (r >> 1);
            float u = acc[mm][cc][r] * bf2f((d2p[idx] >> ((r & 1) * 16)) & 0xffffu);
            dstoreW(PA, mm, cc, r, u);
          }
      __syncthreads();
    }
  }

  // ---------------- log-det epilogue ----------------
#pragma unroll
  for (int r = 0; r < 4; r++) {
    float s = ldacc[r];
    s += __shfl_xor(s, 1);
    s += __shfl_xor(s, 2);
    s += __shfl_xor(s, 4);
    s += __shfl_xor(s, 8);
    ldacc[r] = s;
  }
  if (l15 == 0) {
#pragma unroll
    for (int r = 0; r < 4; r++) {
      int row = mh * 16 + g16 * 4 + r;
      ldp[row * 4 + ctn] = ldacc[r];
    }
  }
  __syncthreads();
  if (tid < 32) {
    float s = ldp[tid * 4] + ldp[tid * 4 + 1] + ldp[tid * 4 + 2] + ldp[tid * 4 + 3];
    int gb = r0 + tid;
    __builtin_nontemporal_store(ldj[gb] + s, out + (size_t)BN * 64 + gb);
  }
}

extern "C" void kernel_launch(void* const* d_in, const int* in_sizes, int n_in,
                              void* d_out, int out_size, void* d_ws, size_t ws_size,
                              hipStream_t stream) {
  const float* y   = (const float*)d_in[0];
  const float* ldj = (const float*)d_in[1];
  const float* v   = (const float*)d_in[2];
  const float* W1  = (const float*)d_in[3];
  const float* b1  = (const float*)d_in[4];
  const float* W2  = (const float*)d_in[5];
  const float* b2  = (const float*)d_in[6];
  const float* W3  = (const float*)d_in[7];
  const float* b3  = (const float*)d_in[8];
  unsigned short* wsb = (unsigned short*)d_ws;
  float* out = (float*)d_out;

  (void)hipFuncSetAttribute(reinterpret_cast<const void*>(&invres_main),
                            hipFuncAttributeMaxDynamicSharedMemorySize, L_SIZE);

  invres_prep<<<N_WS / 256, 256, 0, stream>>>(W1, W2, W3, wsb);
  invres_main<<<BN / 32, 512, L_SIZE, stream>>>(y, ldj, v, b1, b2, b3, wsb, out);
}

// Round 13
// 815.554 us; speedup vs baseline: 2.4557x; 1.0442x over previous
//
#include <hip/hip_runtime.h>

#define BN 262144

typedef short bf16x8 __attribute__((ext_vector_type(8)));
typedef float f32x4 __attribute__((ext_vector_type(4)));

#define MFMA16(a,b,c) __builtin_amdgcn_mfma_f32_16x16x32_bf16((a),(b),(c),0,0,0)

__device__ __forceinline__ unsigned short f2bf(float f) {
  union { float f; unsigned int u; } x; x.f = f;
  unsigned int u = x.u + 0x7fffu + ((x.u >> 16) & 1u);
  return (unsigned short)(u >> 16);
}
__device__ __forceinline__ float bf2f(unsigned int h) {
  union { unsigned int u; float f; } x; x.u = h << 16;
  return x.f;
}
// truncating f32->bf16 (1 VALU op); for staged intermediates
__device__ __forceinline__ unsigned short tbf(float f) {
  union { float f; unsigned int u; } x; x.f = f;
  return (unsigned short)(x.u >> 16);
}
// pack two f32 -> (bf16_lo | bf16_hi<<16), truncating (3 VALU ops)
__device__ __forceinline__ unsigned pk2(float lo, float hi) {
  union { float f; unsigned int u; } a, b; a.f = lo; b.f = hi;
  return (a.u >> 16) | (b.u & 0xffff0000u);
}
// bank-spreading swizzle: (row&7)<<4 XOR (row&8)<<2 — 4 g16-groups hit 4 disjoint bank octets
__device__ __forceinline__ unsigned swz(int row) {
  return (((unsigned)(row & 7)) << 4) ^ (((unsigned)(row & 8)) << 2);
}

// All weight arrays in 16x16x32 B-fragment layout (ushort units):
// elem ((ct*KS+s)*64+lane)*8+j holds B[k][n], n = ct*16+(lane&15), k = s*32+(lane>>4)*8+j
#define O_R1 0        // W1^T: B[k][n]=W1[n*64+k]   K=64  N=256 KS=2
#define O_R2 16384    // W2^T: B[k][n]=W2[n*256+k]  K=256 N=256 KS=8
#define O_R3 81920    // W3^T: B[k][n]=W3[n*256+k]  K=256 N=64  KS=8
#define O_R4 98304    // W3  : B[k][n]=W3[k*256+n]  K=64  N=256 KS=2
#define O_R5 114688   // W2  : B[k][n]=W2[k*256+n]  K=256 N=256 KS=8
#define O_R6 180224   // W1  : B[k][n]=W1[k*64+n]   K=256 N=64  KS=8
#define N_WS 196608

__global__ void invres_prep(const float* __restrict__ W1, const float* __restrict__ W2,
                            const float* __restrict__ W3, unsigned short* __restrict__ wsb) {
  int idx = blockIdx.x * 256 + threadIdx.x;
  if (idx >= N_WS) return;
  int j = idx & 7;
  int lane = (idx >> 3) & 63;
  int nn = lane & 15, kn = (lane >> 4) * 8 + j;
  float val;
  if (idx < O_R2) {                // R1, KS=2
    int g = idx >> 9; int s = g & 1; int ct = g >> 1;
    val = W1[(ct * 16 + nn) * 64 + (s * 32 + kn)];
  } else if (idx < O_R3) {         // R2, KS=8
    int g = (idx - O_R2) >> 9; int s = g & 7; int ct = g >> 3;
    val = W2[(ct * 16 + nn) * 256 + (s * 32 + kn)];
  } else if (idx < O_R4) {         // R3, KS=8
    int g = (idx - O_R3) >> 9; int s = g & 7; int ct = g >> 3;
    val = W3[(ct * 16 + nn) * 256 + (s * 32 + kn)];
  } else if (idx < O_R5) {         // R4, KS=2
    int g = (idx - O_R4) >> 9; int s = g & 1; int ct = g >> 1;
    val = W3[(s * 32 + kn) * 256 + (ct * 16 + nn)];
  } else if (idx < O_R6) {         // R5, KS=8
    int g = (idx - O_R5) >> 9; int s = g & 7; int ct = g >> 3;
    val = W2[(s * 32 + kn) * 256 + (ct * 16 + nn)];
  } else {                         // R6, KS=8
    int g = (idx - O_R6) >> 9; int s = g & 7; int ct = g >> 3;
    val = W1[(s * 32 + kn) * 64 + (ct * 16 + nn)];
  }
  wsb[idx] = f2bf(val);
}

// LDS (per block, M=32), buffers aliased across phases:
//  PA 32x256 bf16 swz (16K): h1 (G1 out, G2 in) then u2 (G4/G4' out, G5 in)
//  PB 32x256 bf16 swz (16K): h2 (G2 out, G3 in) then u1 (G5 out, G6 in)
//  WB 32x64  bf16 swz (4K) : w  (G6 out, G4' in)
//  LDP f32[32][4] (512B)
#define L_PB  16384
#define L_WB  32768
#define L_LDP 36864
#define L_SIZE 37376

__global__ void __launch_bounds__(512, 4)
invres_main(const float* __restrict__ y, const float* __restrict__ ldj,
            const float* __restrict__ v, const float* __restrict__ b1,
            const float* __restrict__ b2, const float* __restrict__ b3,
            const unsigned short* __restrict__ wsb, float* __restrict__ out) {
  extern __shared__ char smem[];
  char* PA = smem;
  char* PB = smem + L_PB;
  char* WB = smem + L_WB;
  float* ldp = (float*)(smem + L_LDP);

  const int tid = threadIdx.x;
  const int lane = tid & 63;
  const int wid = tid >> 6;          // 0..7
  const int l15 = lane & 15, g16 = lane >> 4;
  const int ct0 = wid * 2;           // wide: col tiles ct0, ct0+1 (32 cols)
  const int mh = wid >> 2;           // narrow: row half (16 rows)
  const int ctn = wid & 3;           // narrow: col tile (16 cols)
  const int r0 = blockIdx.x * 32;

  const bf16x8* R1 = (const bf16x8*)(wsb + O_R1);
  const bf16x8* R2 = (const bf16x8*)(wsb + O_R2);
  const bf16x8* R3 = (const bf16x8*)(wsb + O_R3);
  const bf16x8* R4 = (const bf16x8*)(wsb + O_R4);
  const bf16x8* R5 = (const bf16x8*)(wsb + O_R5);
  const bf16x8* R6 = (const bf16x8*)(wsb + O_R6);

  // A-fragment (16x16x32) from 32x256 swizzled LDS buffer
  auto ldsA = [&](const char* buf, int mm, int s) -> bf16x8 {
    int row = mm * 16 + l15;
    unsigned byte = ((unsigned)(s * 64 + g16 * 16)) ^ swz(row);
    return *(const bf16x8*)(buf + row * 512 + byte);
  };
  // D-layout truncating store into 32x256 swizzled LDS buffer (wide phases)
  auto dstoreW = [&](char* buf, int mm, int cc, int r, float val) {
    int row = mm * 16 + g16 * 4 + r;
    int col = (ct0 + cc) * 16 + l15;
    *(unsigned short*)(buf + row * 512 + (((unsigned)(col * 2)) ^ swz(row))) = tbf(val);
  };
  // global A-fragment from y/v (row-major fp32), NT
  auto gA = [&](const float* p, int mm, int s, bool elu) -> bf16x8 {
    const float* q = p + (size_t)(r0 + mm * 16 + l15) * 64 + s * 32 + g16 * 8;
    f32x4 a = __builtin_nontemporal_load((const f32x4*)q);
    f32x4 b = __builtin_nontemporal_load((const f32x4*)(q + 4));
    float xv[8] = {a[0], a[1], a[2], a[3], b[0], b[1], b[2], b[3]};
    bf16x8 f;
#pragma unroll
    for (int i = 0; i < 8; i++) {
      float x = xv[i];
      if (elu) x = x > 0.f ? x : (__expf(x) - 1.f);
      f[i] = (short)f2bf(x);
    }
    return f;
  };

  float bb1[2], bb2[2];
#pragma unroll
  for (int cc = 0; cc < 2; cc++) {
    bb1[cc] = b1[(ct0 + cc) * 16 + l15];
    bb2[cc] = b2[(ct0 + cc) * 16 + l15];
  }
  const float bb3 = b3[ctn * 16 + l15];

  unsigned d1p[8], d2p[8], d0p[2], v0p[2];
  float ldacc[4] = {0.f, 0.f, 0.f, 0.f};

  // ---------------- G1: h1 = elu(elu(y) @ W1^T + b1) -> PA ; d1 -> regs ----------------
  {
    f32x4 acc[2][2] = {};
#pragma unroll
    for (int s = 0; s < 2; s++) {
      bf16x8 a0 = gA(y, 0, s, true);
      bf16x8 a1 = gA(y, 1, s, true);
#pragma unroll
      for (int cc = 0; cc < 2; cc++) {
        bf16x8 B = R1[((ct0 + cc) * 2 + s) * 64 + lane];
        acc[0][cc] = MFMA16(a0, B, acc[0][cc]);
        acc[1][cc] = MFMA16(a1, B, acc[1][cc]);
      }
    }
#pragma unroll
    for (int mm = 0; mm < 2; mm++)
#pragma unroll
      for (int cc = 0; cc < 2; cc++) {
        float dv[4];
#pragma unroll
        for (int r = 0; r < 4; r++) {
          float a = acc[mm][cc][r] + bb1[cc];
          float e = __expf(a);
          float h = a > 0.f ? a : (e - 1.f);
          dv[r] = a > 0.f ? 1.f : e;
          dstoreW(PA, mm, cc, r, h);
        }
        int base = (mm * 2 + cc) * 2;
        d1p[base] = pk2(dv[0], dv[1]);
        d1p[base + 1] = pk2(dv[2], dv[3]);
      }
  }
  __syncthreads();

  // ---------------- G2: h2 = elu(h1 @ W2^T + b2) -> PB ; d2 -> regs ----------------
  {
    f32x4 acc[2][2] = {};
#pragma unroll 1
    for (int s = 0; s < 8; s++) {
      bf16x8 a0 = ldsA(PA, 0, s);
      bf16x8 a1 = ldsA(PA, 1, s);
      bf16x8 B0 = R2[(ct0 * 8 + s) * 64 + lane];
      bf16x8 B1 = R2[((ct0 + 1) * 8 + s) * 64 + lane];
      acc[0][0] = MFMA16(a0, B0, acc[0][0]);
      acc[0][1] = MFMA16(a0, B1, acc[0][1]);
      acc[1][0] = MFMA16(a1, B0, acc[1][0]);
      acc[1][1] = MFMA16(a1, B1, acc[1][1]);
    }
#pragma unroll
    for (int mm = 0; mm < 2; mm++)
#pragma unroll
      for (int cc = 0; cc < 2; cc++) {
        float dv[4];
#pragma unroll
        for (int r = 0; r < 4; r++) {
          float a = acc[mm][cc][r] + bb2[cc];
          float e = __expf(a);
          float h = a > 0.f ? a : (e - 1.f);
          dv[r] = a > 0.f ? 1.f : e;
          dstoreW(PB, mm, cc, r, h);
        }
        int base = (mm * 2 + cc) * 2;
        d2p[base] = pk2(dv[0], dv[1]);
        d2p[base + 1] = pk2(dv[2], dv[3]);
      }
  }
  __syncthreads();

  // ---------------- G3: z = y + h2 @ W3^T + b3 ; d0, v0 ----------------
  {
    f32x4 acc0 = {}, acc1 = {};
#pragma unroll 1
    for (int s = 0; s < 8; s += 2) {
      acc0 = MFMA16(ldsA(PB, mh, s), R3[(ctn * 8 + s) * 64 + lane], acc0);
      acc1 = MFMA16(ldsA(PB, mh, s + 1), R3[(ctn * 8 + s + 1) * 64 + lane], acc1);
    }
    float d0v[4], v0v[4];
#pragma unroll
    for (int r = 0; r < 4; r++) {
      float av = acc0[r] + acc1[r];
      int row = r0 + mh * 16 + g16 * 4 + r;
      int col = ctn * 16 + l15;
      size_t off = (size_t)row * 64 + col;
      float yv = __builtin_nontemporal_load(y + off);
      __builtin_nontemporal_store(yv + av + bb3, out + off);
      d0v[r] = yv > 0.f ? 1.f : __expf(yv);
      v0v[r] = __builtin_nontemporal_load(v + off);
    }
    d0p[0] = pk2(d0v[0], d0v[1]); d0p[1] = pk2(d0v[2], d0v[3]);
    v0p[0] = pk2(v0v[0], v0v[1]); v0p[1] = pk2(v0v[2], v0v[3]);
  }

  // ---------------- G4 (k=1): u2 = (v0 @ W3) * d2 -> PA ----------------
  {
    f32x4 acc[2][2] = {};
#pragma unroll
    for (int s = 0; s < 2; s++) {
      bf16x8 a0 = gA(v, 0, s, false);
      bf16x8 a1 = gA(v, 1, s, false);
#pragma unroll
      for (int cc = 0; cc < 2; cc++) {
        bf16x8 B = R4[((ct0 + cc) * 2 + s) * 64 + lane];
        acc[0][cc] = MFMA16(a0, B, acc[0][cc]);
        acc[1][cc] = MFMA16(a1, B, acc[1][cc]);
      }
    }
#pragma unroll
    for (int mm = 0; mm < 2; mm++)
#pragma unroll
      for (int cc = 0; cc < 2; cc++)
#pragma unroll
        for (int r = 0; r < 4; r++) {
          int idx = (mm * 2 + cc) * 2 + (r >> 1);
          float u = acc[mm][cc][r] * bf2f((d2p[idx] >> ((r & 1) * 16)) & 0xffffu);
          dstoreW(PA, mm, cc, r, u);
        }
  }
  __syncthreads();

  // ---------------- backward iterations ----------------
  for (int k = 1; k <= 8; ++k) {
    // G5: u1 = (u2 @ W2) * d1 -> PB
    {
      f32x4 acc[2][2] = {};
#pragma unroll 1
      for (int s = 0; s < 8; s++) {
        bf16x8 a0 = ldsA(PA, 0, s);
        bf16x8 a1 = ldsA(PA, 1, s);
        bf16x8 B0 = R5[(ct0 * 8 + s) * 64 + lane];
        bf16x8 B1 = R5[((ct0 + 1) * 8 + s) * 64 + lane];
        acc[0][0] = MFMA16(a0, B0, acc[0][0]);
        acc[0][1] = MFMA16(a0, B1, acc[0][1]);
        acc[1][0] = MFMA16(a1, B0, acc[1][0]);
        acc[1][1] = MFMA16(a1, B1, acc[1][1]);
      }
#pragma unroll
      for (int mm = 0; mm < 2; mm++)
#pragma unroll
        for (int cc = 0; cc < 2; cc++)
#pragma unroll
          for (int r = 0; r < 4; r++) {
            int idx = (mm * 2 + cc) * 2 + (r >> 1);
            float u = acc[mm][cc][r] * bf2f((d1p[idx] >> ((r & 1) * 16)) & 0xffffu);
            dstoreW(PB, mm, cc, r, u);
          }
    }
    __syncthreads();

    // G6: w' = (u1 @ W1) * d0 ; log-det ; w' -> WB
    {
      float coef = (k & 1) ? (1.f / (float)k) : (-1.f / (float)k);
      f32x4 acc0 = {}, acc1 = {};
#pragma unroll 1
      for (int s = 0; s < 8; s += 2) {
        acc0 = MFMA16(ldsA(PB, mh, s), R6[(ctn * 8 + s) * 64 + lane], acc0);
        acc1 = MFMA16(ldsA(PB, mh, s + 1), R6[(ctn * 8 + s + 1) * 64 + lane], acc1);
      }
#pragma unroll
      for (int r = 0; r < 4; r++) {
        float wv = (acc0[r] + acc1[r]) * bf2f((d0p[r >> 1] >> ((r & 1) * 16)) & 0xffffu);
        ldacc[r] += coef * wv * bf2f((v0p[r >> 1] >> ((r & 1) * 16)) & 0xffffu);
        if (k < 8) {
          int row = mh * 16 + g16 * 4 + r;
          int col = ctn * 16 + l15;
          *(unsigned short*)(WB + row * 128 + (((unsigned)(col * 2)) ^ swz(row))) = tbf(wv);
        }
      }
    }
    if (k < 8) {
      __syncthreads();
      // G4': u2 = (w' @ W3) * d2 -> PA
      f32x4 acc[2][2] = {};
#pragma unroll
      for (int s = 0; s < 2; s++) {
        bf16x8 a0, a1;
#pragma unroll
        for (int mm = 0; mm < 2; mm++) {
          int row = mm * 16 + l15;
          unsigned byte = ((unsigned)(s * 64 + g16 * 16)) ^ swz(row);
          bf16x8 a = *(const bf16x8*)(WB + row * 128 + byte);
          if (mm == 0) a0 = a; else a1 = a;
        }
#pragma unroll
        for (int cc = 0; cc < 2; cc++) {
          bf16x8 B = R4[((ct0 + cc) * 2 + s) * 64 + lane];
          acc[0][cc] = MFMA16(a0, B, acc[0][cc]);
          acc[1][cc] = MFMA16(a1, B, acc[1][cc]);
        }
      }
#pragma unroll
      for (int mm = 0; mm < 2; mm++)
#pragma unroll
        for (int cc = 0; cc < 2; cc++)
#pragma unroll
          for (int r = 0; r < 4; r++) {
            int idx = (mm * 2 + cc) * 2 + (r >> 1);
            float u = acc[mm][cc][r] * bf2f((d2p[idx] >> ((r & 1) * 16)) & 0xffffu);
            dstoreW(PA, mm, cc, r, u);
          }
      __syncthreads();
    }
  }

  // ---------------- log-det epilogue ----------------
#pragma unroll
  for (int r = 0; r < 4; r++) {
    float s = ldacc[r];
    s += __shfl_xor(s, 1);
    s += __shfl_xor(s, 2);
    s += __shfl_xor(s, 4);
    s += __shfl_xor(s, 8);
    ldacc[r] = s;
  }
  if (l15 == 0) {
#pragma unroll
    for (int r = 0; r < 4; r++) {
      int row = mh * 16 + g16 * 4 + r;
      ldp[row * 4 + ctn] = ldacc[r];
    }
  }
  __syncthreads();
  if (tid < 32) {
    float s = ldp[tid * 4] + ldp[tid * 4 + 1] + ldp[tid * 4 + 2] + ldp[tid * 4 + 3];
    int gb = r0 + tid;
    __builtin_nontemporal_store(ldj[gb] + s, out + (size_t)BN * 64 + gb);
  }
}

extern "C" void kernel_launch(void* const* d_in, const int* in_sizes, int n_in,
                              void* d_out, int out_size, void* d_ws, size_t ws_size,
                              hipStream_t stream) {
  const float* y   = (const float*)d_in[0];
  const float* ldj = (const float*)d_in[1];
  const float* v   = (const float*)d_in[2];
  const float* W1  = (const float*)d_in[3];
  const float* b1  = (const float*)d_in[4];
  const float* W2  = (const float*)d_in[5];
  const float* b2  = (const float*)d_in[6];
  const float* W3  = (const float*)d_in[7];
  const float* b3  = (const float*)d_in[8];
  unsigned short* wsb = (unsigned short*)d_ws;
  float* out = (float*)d_out;

  (void)hipFuncSetAttribute(reinterpret_cast<const void*>(&invres_main),
                            hipFuncAttributeMaxDynamicSharedMemorySize, L_SIZE);

  invres_prep<<<N_WS / 256, 256, 0, stream>>>(W1, W2, W3, wsb);
  invres_main<<<BN / 32, 512, L_SIZE, stream>>>(y, ldj, v, b1, b2, b3, wsb, out);
}

// Round 15
// 813.777 us; speedup vs baseline: 2.4610x; 1.0022x over previous
//
#include <hip/hip_runtime.h>

#define BN 262144

typedef short bf16x8 __attribute__((ext_vector_type(8)));
typedef float f32x4 __attribute__((ext_vector_type(4)));
typedef unsigned int u32x2 __attribute__((ext_vector_type(2)));

#define MFMA16(a,b,c) __builtin_amdgcn_mfma_f32_16x16x32_bf16((a),(b),(c),0,0,0)

__device__ __forceinline__ unsigned short f2bf(float f) {
  union { float f; unsigned int u; } x; x.f = f;
  unsigned int u = x.u + 0x7fffu + ((x.u >> 16) & 1u);
  return (unsigned short)(u >> 16);
}
__device__ __forceinline__ float bf2f(unsigned int h) {
  union { unsigned int u; float f; } x; x.u = h << 16;
  return x.f;
}
// truncating f32->bf16 (1 VALU op); for staged intermediates
__device__ __forceinline__ unsigned short tbf(float f) {
  union { float f; unsigned int u; } x; x.f = f;
  return (unsigned short)(x.u >> 16);
}
// pack two f32 -> (bf16_lo | bf16_hi<<16), truncating (3 VALU ops)
__device__ __forceinline__ unsigned pk2(float lo, float hi) {
  union { float f; unsigned int u; } a, b; a.f = lo; b.f = hi;
  return (a.u >> 16) | (b.u & 0xffff0000u);
}
__device__ __forceinline__ unsigned swz(int row) {
  return (((unsigned)(row & 7)) << 4) ^ (((unsigned)(row & 8)) << 2);
}

// All weight arrays in 16x16x32 B-fragment layout (ushort units):
// elem ((ct*KS+s)*64+lane)*8+j holds B[k][n], n = ct*16+(lane&15), k = s*32+(lane>>4)*8+j
#define O_R1 0        // W1^T: B[k][n]=W1[n*64+k]   K=64  N=256 KS=2
#define O_R2 16384    // W2^T: B[k][n]=W2[n*256+k]  K=256 N=256 KS=8
#define O_R3 81920    // W3^T: B[k][n]=W3[n*256+k]  K=256 N=64  KS=8
#define O_R4 98304    // W3  : B[k][n]=W3[k*256+n]  K=64  N=256 KS=2
#define O_R5 114688   // W2  : B[k][n]=W2[k*256+n]  K=256 N=256 KS=8
#define O_R6 180224   // W1  : B[k][n]=W1[k*64+n]   K=256 N=64  KS=8
#define N_WS 196608

__global__ void invres_prep(const float* __restrict__ W1, const float* __restrict__ W2,
                            const float* __restrict__ W3, unsigned short* __restrict__ wsb) {
  int idx = blockIdx.x * 256 + threadIdx.x;
  if (idx >= N_WS) return;
  int j = idx & 7;
  int lane = (idx >> 3) & 63;
  int nn = lane & 15, kn = (lane >> 4) * 8 + j;
  float val;
  if (idx < O_R2) {                // R1, KS=2
    int g = idx >> 9; int s = g & 1; int ct = g >> 1;
    val = W1[(ct * 16 + nn) * 64 + (s * 32 + kn)];
  } else if (idx < O_R3) {         // R2, KS=8
    int g = (idx - O_R2) >> 9; int s = g & 7; int ct = g >> 3;
    val = W2[(ct * 16 + nn) * 256 + (s * 32 + kn)];
  } else if (idx < O_R4) {         // R3, KS=8
    int g = (idx - O_R3) >> 9; int s = g & 7; int ct = g >> 3;
    val = W3[(ct * 16 + nn) * 256 + (s * 32 + kn)];
  } else if (idx < O_R5) {         // R4, KS=2
    int g = (idx - O_R4) >> 9; int s = g & 1; int ct = g >> 1;
    val = W3[(s * 32 + kn) * 256 + (ct * 16 + nn)];
  } else if (idx < O_R6) {         // R5, KS=8
    int g = (idx - O_R5) >> 9; int s = g & 7; int ct = g >> 3;
    val = W2[(s * 32 + kn) * 256 + (ct * 16 + nn)];
  } else {                         // R6, KS=8
    int g = (idx - O_R6) >> 9; int s = g & 7; int ct = g >> 3;
    val = W1[(s * 32 + kn) * 64 + (ct * 16 + nn)];
  }
  wsb[idx] = f2bf(val);
}

// LDS (per block, M=32):
//  PA 32x256 bf16 swz (16K): h1 then u2        PB (16K): h2 then u1
//  WB 32x64  bf16 swz (4K) : w
//  D1/D2 (16K each): elu' masks, thread-private b64 granules [wid][mc][lane]
//  LDP f32[32][4] (512B)
#define L_PB  16384
#define L_WB  32768
#define L_D1  36864
#define L_D2  53248
#define L_LDP 69632
#define L_SIZE 70144

__global__ void __launch_bounds__(512, 4)
invres_main(const float* __restrict__ y, const float* __restrict__ ldj,
            const float* __restrict__ v, const float* __restrict__ b1,
            const float* __restrict__ b2, const float* __restrict__ b3,
            const unsigned short* __restrict__ wsb, float* __restrict__ out) {
  extern __shared__ char smem[];
  char* PA = smem;
  char* PB = smem + L_PB;
  char* WB = smem + L_WB;
  char* D1 = smem + L_D1;
  char* D2 = smem + L_D2;
  float* ldp = (float*)(smem + L_LDP);

  const int tid = threadIdx.x;
  const int lane = tid & 63;
  const int wid = tid >> 6;          // 0..7
  const int l15 = lane & 15, g16 = lane >> 4;
  const int ct0 = wid * 2;           // wide: col tiles ct0, ct0+1 (32 cols)
  const int mh = wid >> 2;           // narrow: row half (16 rows)
  const int ctn = wid & 3;           // narrow: col tile (16 cols)
  const int r0 = blockIdx.x * 32;

  const bf16x8* R1 = (const bf16x8*)(wsb + O_R1);
  const bf16x8* R2 = (const bf16x8*)(wsb + O_R2);
  const bf16x8* R3 = (const bf16x8*)(wsb + O_R3);
  const bf16x8* R4 = (const bf16x8*)(wsb + O_R4);
  const bf16x8* R5 = (const bf16x8*)(wsb + O_R5);
  const bf16x8* R6 = (const bf16x8*)(wsb + O_R6);

  // mask granule byte offset (thread-private slot): [wid][mc][lane] x 8B
  auto mOff = [&](int mc) -> int { return ((wid * 4 + mc) * 64 + lane) * 8; };

  // A-fragment (16x16x32) from 32x256 swizzled LDS buffer
  auto ldsA = [&](const char* buf, int mm, int s) -> bf16x8 {
    int row = mm * 16 + l15;
    unsigned byte = ((unsigned)(s * 64 + g16 * 16)) ^ swz(row);
    return *(const bf16x8*)(buf + row * 512 + byte);
  };
  // D-layout truncating store into 32x256 swizzled LDS buffer (wide phases)
  auto dstoreW = [&](char* buf, int mm, int cc, int r, float val) {
    int row = mm * 16 + g16 * 4 + r;
    int col = (ct0 + cc) * 16 + l15;
    *(unsigned short*)(buf + row * 512 + (((unsigned)(col * 2)) ^ swz(row))) = tbf(val);
  };
  // global A-fragment from y/v (row-major fp32), NT
  auto gA = [&](const float* p, int mm, int s, bool elu) -> bf16x8 {
    const float* q = p + (size_t)(r0 + mm * 16 + l15) * 64 + s * 32 + g16 * 8;
    f32x4 a = __builtin_nontemporal_load((const f32x4*)q);
    f32x4 b = __builtin_nontemporal_load((const f32x4*)(q + 4));
    float xv[8] = {a[0], a[1], a[2], a[3], b[0], b[1], b[2], b[3]};
    bf16x8 f;
#pragma unroll
    for (int i = 0; i < 8; i++) {
      float x = xv[i];
      if (elu) x = x > 0.f ? x : (__expf(x) - 1.f);
      f[i] = (short)f2bf(x);
    }
    return f;
  };

  float bb1[2], bb2[2];
#pragma unroll
  for (int cc = 0; cc < 2; cc++) {
    bb1[cc] = b1[(ct0 + cc) * 16 + l15];
    bb2[cc] = b2[(ct0 + cc) * 16 + l15];
  }
  const float bb3 = b3[ctn * 16 + l15];

  unsigned d0p[2], v0p[2];
  float ldacc[4] = {0.f, 0.f, 0.f, 0.f};

  // ---------------- G1: h1 = elu(elu(y) @ W1^T + b1) -> PA ; d1 -> D1 ----------------
  {
    f32x4 acc[2][2] = {};
#pragma unroll
    for (int s = 0; s < 2; s++) {
      bf16x8 a0 = gA(y, 0, s, true);
      bf16x8 a1 = gA(y, 1, s, true);
#pragma unroll
      for (int cc = 0; cc < 2; cc++) {
        bf16x8 B = R1[((ct0 + cc) * 2 + s) * 64 + lane];
        acc[0][cc] = MFMA16(a0, B, acc[0][cc]);
        acc[1][cc] = MFMA16(a1, B, acc[1][cc]);
      }
    }
#pragma unroll
    for (int mm = 0; mm < 2; mm++)
#pragma unroll
      for (int cc = 0; cc < 2; cc++) {
        float dv[4];
#pragma unroll
        for (int r = 0; r < 4; r++) {
          float a = acc[mm][cc][r] + bb1[cc];
          float e = __expf(a);
          float h = a > 0.f ? a : (e - 1.f);
          dv[r] = a > 0.f ? 1.f : e;
          dstoreW(PA, mm, cc, r, h);
        }
        u32x2 w; w[0] = pk2(dv[0], dv[1]); w[1] = pk2(dv[2], dv[3]);
        *(u32x2*)(D1 + mOff(mm * 2 + cc)) = w;
      }
  }
  __syncthreads();

  // ---------------- G2: h2 = elu(h1 @ W2^T + b2) -> PB ; d2 -> D2 ----------------
  {
    f32x4 acc[2][2] = {};
    bf16x8 a0 = ldsA(PA, 0, 0);
    bf16x8 a1 = ldsA(PA, 1, 0);
#pragma unroll 1
    for (int s = 0; s < 8; s++) {
      bf16x8 c0 = a0, c1 = a1;
      int sn = s < 7 ? s + 1 : 7;
      a0 = ldsA(PA, 0, sn);
      a1 = ldsA(PA, 1, sn);
      bf16x8 B0 = R2[(ct0 * 8 + s) * 64 + lane];
      bf16x8 B1 = R2[((ct0 + 1) * 8 + s) * 64 + lane];
      acc[0][0] = MFMA16(c0, B0, acc[0][0]);
      acc[0][1] = MFMA16(c0, B1, acc[0][1]);
      acc[1][0] = MFMA16(c1, B0, acc[1][0]);
      acc[1][1] = MFMA16(c1, B1, acc[1][1]);
    }
#pragma unroll
    for (int mm = 0; mm < 2; mm++)
#pragma unroll
      for (int cc = 0; cc < 2; cc++) {
        float dv[4];
#pragma unroll
        for (int r = 0; r < 4; r++) {
          float a = acc[mm][cc][r] + bb2[cc];
          float e = __expf(a);
          float h = a > 0.f ? a : (e - 1.f);
          dv[r] = a > 0.f ? 1.f : e;
          dstoreW(PB, mm, cc, r, h);
        }
        u32x2 w; w[0] = pk2(dv[0], dv[1]); w[1] = pk2(dv[2], dv[3]);
        *(u32x2*)(D2 + mOff(mm * 2 + cc)) = w;
      }
  }
  __syncthreads();

  // ---------------- G3: z = y + h2 @ W3^T + b3 ; d0, v0 ----------------
  {
    f32x4 acc0 = {}, acc1 = {};
    bf16x8 p0 = ldsA(PB, mh, 0);
    bf16x8 p1 = ldsA(PB, mh, 1);
#pragma unroll 1
    for (int s = 0; s < 8; s += 2) {
      bf16x8 c0 = p0, c1 = p1;
      int sn = s + 2 < 8 ? s + 2 : 0;
      p0 = ldsA(PB, mh, sn);
      p1 = ldsA(PB, mh, sn + 1);
      acc0 = MFMA16(c0, R3[(ctn * 8 + s) * 64 + lane], acc0);
      acc1 = MFMA16(c1, R3[(ctn * 8 + s + 1) * 64 + lane], acc1);
    }
    float d0v[4], v0v[4];
#pragma unroll
    for (int r = 0; r < 4; r++) {
      float av = acc0[r] + acc1[r];
      int row = r0 + mh * 16 + g16 * 4 + r;
      int col = ctn * 16 + l15;
      size_t off = (size_t)row * 64 + col;
      float yv = __builtin_nontemporal_load(y + off);
      __builtin_nontemporal_store(yv + av + bb3, out + off);
      d0v[r] = yv > 0.f ? 1.f : __expf(yv);
      v0v[r] = __builtin_nontemporal_load(v + off);
    }
    d0p[0] = pk2(d0v[0], d0v[1]); d0p[1] = pk2(d0v[2], d0v[3]);
    v0p[0] = pk2(v0v[0], v0v[1]); v0p[1] = pk2(v0v[2], v0v[3]);
  }

  // ---------------- G4 (k=1): u2 = (v0 @ W3) * d2 -> PA ----------------
  {
    f32x4 acc[2][2] = {};
#pragma unroll
    for (int s = 0; s < 2; s++) {
      bf16x8 a0 = gA(v, 0, s, false);
      bf16x8 a1 = gA(v, 1, s, false);
#pragma unroll
      for (int cc = 0; cc < 2; cc++) {
        bf16x8 B = R4[((ct0 + cc) * 2 + s) * 64 + lane];
        acc[0][cc] = MFMA16(a0, B, acc[0][cc]);
        acc[1][cc] = MFMA16(a1, B, acc[1][cc]);
      }
    }
#pragma unroll
    for (int mm = 0; mm < 2; mm++)
#pragma unroll
      for (int cc = 0; cc < 2; cc++) {
        u32x2 dd = *(const u32x2*)(D2 + mOff(mm * 2 + cc));
#pragma unroll
        for (int r = 0; r < 4; r++) {
          float u = acc[mm][cc][r] * bf2f((dd[r >> 1] >> ((r & 1) * 16)) & 0xffffu);
          dstoreW(PA, mm, cc, r, u);
        }
      }
  }
  __syncthreads();

  // ---------------- backward iterations ----------------
  for (int k = 1; k <= 8; ++k) {
    // G5: u1 = (u2 @ W2) * d1 -> PB
    {
      f32x4 acc[2][2] = {};
      bf16x8 a0 = ldsA(PA, 0, 0);
      bf16x8 a1 = ldsA(PA, 1, 0);
#pragma unroll 1
      for (int s = 0; s < 8; s++) {
        bf16x8 c0 = a0, c1 = a1;
        int sn = s < 7 ? s + 1 : 7;
        a0 = ldsA(PA, 0, sn);
        a1 = ldsA(PA, 1, sn);
        bf16x8 B0 = R5[(ct0 * 8 + s) * 64 + lane];
        bf16x8 B1 = R5[((ct0 + 1) * 8 + s) * 64 + lane];
        acc[0][0] = MFMA16(c0, B0, acc[0][0]);
        acc[0][1] = MFMA16(c0, B1, acc[0][1]);
        acc[1][0] = MFMA16(c1, B0, acc[1][0]);
        acc[1][1] = MFMA16(c1, B1, acc[1][1]);
      }
#pragma unroll
      for (int mm = 0; mm < 2; mm++)
#pragma unroll
        for (int cc = 0; cc < 2; cc++) {
          u32x2 dd = *(const u32x2*)(D1 + mOff(mm * 2 + cc));
#pragma unroll
          for (int r = 0; r < 4; r++) {
            float u = acc[mm][cc][r] * bf2f((dd[r >> 1] >> ((r & 1) * 16)) & 0xffffu);
            dstoreW(PB, mm, cc, r, u);
          }
        }
    }
    __syncthreads();

    // G6: w' = (u1 @ W1) * d0 ; log-det ; w' -> WB
    {
      float coef = (k & 1) ? (1.f / (float)k) : (-1.f / (float)k);
      f32x4 acc0 = {}, acc1 = {};
      bf16x8 p0 = ldsA(PB, mh, 0);
      bf16x8 p1 = ldsA(PB, mh, 1);
#pragma unroll 1
      for (int s = 0; s < 8; s += 2) {
        bf16x8 c0 = p0, c1 = p1;
        int sn = s + 2 < 8 ? s + 2 : 0;
        p0 = ldsA(PB, mh, sn);
        p1 = ldsA(PB, mh, sn + 1);
        acc0 = MFMA16(c0, R6[(ctn * 8 + s) * 64 + lane], acc0);
        acc1 = MFMA16(c1, R6[(ctn * 8 + s + 1) * 64 + lane], acc1);
      }
#pragma unroll
      for (int r = 0; r < 4; r++) {
        float wv = (acc0[r] + acc1[r]) * bf2f((d0p[r >> 1] >> ((r & 1) * 16)) & 0xffffu);
        ldacc[r] += coef * wv * bf2f((v0p[r >> 1] >> ((r & 1) * 16)) & 0xffffu);
        if (k < 8) {
          int row = mh * 16 + g16 * 4 + r;
          int col = ctn * 16 + l15;
          *(unsigned short*)(WB + row * 128 + (((unsigned)(col * 2)) ^ swz(row))) = tbf(wv);
        }
      }
    }
    if (k < 8) {
      __syncthreads();
      // G4': u2 = (w' @ W3) * d2 -> PA
      f32x4 acc[2][2] = {};
#pragma unroll
      for (int s = 0; s < 2; s++) {
        bf16x8 a0, a1;
#pragma unroll
        for (int mm = 0; mm < 2; mm++) {
          int row = mm * 16 + l15;
          unsigned byte = ((unsigned)(s * 64 + g16 * 16)) ^ swz(row);
          bf16x8 a = *(const bf16x8*)(WB + row * 128 + byte);
          if (mm == 0) a0 = a; else a1 = a;
        }
#pragma unroll
        for (int cc = 0; cc < 2; cc++) {
          bf16x8 B = R4[((ct0 + cc) * 2 + s) * 64 + lane];
          acc[0][cc] = MFMA16(a0, B, acc[0][cc]);
          acc[1][cc] = MFMA16(a1, B, acc[1][cc]);
        }
      }
#pragma unroll
      for (int mm = 0; mm < 2; mm++)
#pragma unroll
        for (int cc = 0; cc < 2; cc++) {
          u32x2 dd = *(const u32x2*)(D2 + mOff(mm * 2 + cc));
#pragma unroll
          for (int r = 0; r < 4; r++) {
            float u = acc[mm][cc][r] * bf2f((dd[r >> 1] >> ((r & 1) * 16)) & 0xffffu);
            dstoreW(PA, mm, cc, r, u);
          }
        }
      __syncthreads();
    }
  }

  // ---------------- log-det epilogue ----------------
#pragma unroll
  for (int r = 0; r < 4; r++) {
    float s = ldacc[r];
    s += __shfl_xor(s, 1);
    s += __shfl_xor(s, 2);
    s += __shfl_xor(s, 4);
    s += __shfl_xor(s, 8);
    ldacc[r] = s;
  }
  if (l15 == 0) {
#pragma unroll
    for (int r = 0; r < 4; r++) {
      int row = mh * 16 + g16 * 4 + r;
      ldp[row * 4 + ctn] = ldacc[r];
    }
  }
  __syncthreads();
  if (tid < 32) {
    float s = ldp[tid * 4] + ldp[tid * 4 + 1] + ldp[tid * 4 + 2] + ldp[tid * 4 + 3];
    int gb = r0 + tid;
    __builtin_nontemporal_store(ldj[gb] + s, out + (size_t)BN * 64 + gb);
  }
}

extern "C" void kernel_launch(void* const* d_in, const int* in_sizes, int n_in,
                              void* d_out, int out_size, void* d_ws, size_t ws_size,
                              hipStream_t stream) {
  const float* y   = (const float*)d_in[0];
  const float* ldj = (const float*)d_in[1];
  const float* v   = (const float*)d_in[2];
  const float* W1  = (const float*)d_in[3];
  const float* b1  = (const float*)d_in[4];
  const float* W2  = (const float*)d_in[5];
  const float* b2  = (const float*)d_in[6];
  const float* W3  = (const float*)d_in[7];
  const float* b3  = (const float*)d_in[8];
  unsigned short* wsb = (unsigned short*)d_ws;
  float* out = (float*)d_out;

  (void)hipFuncSetAttribute(reinterpret_cast<const void*>(&invres_main),
                            hipFuncAttributeMaxDynamicSharedMemorySize, L_SIZE);

  invres_prep<<<N_WS / 256, 256, 0, stream>>>(W1, W2, W3, wsb);
  invres_main<<<BN / 32, 512, L_SIZE, stream>>>(y, ldj, v, b1, b2, b3, wsb, out);
}

// Round 16
// 806.361 us; speedup vs baseline: 2.4837x; 1.0092x over previous
//
#include <hip/hip_runtime.h>

#define BN 262144

typedef short bf16x8 __attribute__((ext_vector_type(8)));
typedef float f32x4 __attribute__((ext_vector_type(4)));
typedef unsigned int u32x2 __attribute__((ext_vector_type(2)));

#define MFMA16(a,b,c) __builtin_amdgcn_mfma_f32_16x16x32_bf16((a),(b),(c),0,0,0)

__device__ __forceinline__ unsigned short f2bf(float f) {
  union { float f; unsigned int u; } x; x.f = f;
  unsigned int u = x.u + 0x7fffu + ((x.u >> 16) & 1u);
  return (unsigned short)(u >> 16);
}
__device__ __forceinline__ float bf2f(unsigned int h) {
  union { unsigned int u; float f; } x; x.u = h << 16;
  return x.f;
}
// pack two f32 -> (bf16_lo | bf16_hi<<16), truncating (3 VALU ops)
__device__ __forceinline__ unsigned pk2(float lo, float hi) {
  union { float f; unsigned int u; } a, b; a.f = lo; b.f = hi;
  return (a.u >> 16) | (b.u & 0xffff0000u);
}
__device__ __forceinline__ unsigned swz(int row) {
  return (((unsigned)(row & 7)) << 4) ^ (((unsigned)(row & 8)) << 2);
}

// All weight arrays in 16x16x32 fragment layout (ushort units); used as the
// MFMA *A*-operand (operand-swapped scheme): i=n=ct*16+(lane&15), k=s*32+(lane>>4)*8+j
#define O_R1 0        // W1^T: [k][n]=W1[n*64+k]   K=64  N=256 KS=2
#define O_R2 16384    // W2^T: [k][n]=W2[n*256+k]  K=256 N=256 KS=8
#define O_R3 81920    // W3^T: [k][n]=W3[n*256+k]  K=256 N=64  KS=8
#define O_R4 98304    // W3  : [k][n]=W3[k*256+n]  K=64  N=256 KS=2
#define O_R5 114688   // W2  : [k][n]=W2[k*256+n]  K=256 N=256 KS=8
#define O_R6 180224   // W1  : [k][n]=W1[k*64+n]   K=256 N=64  KS=8
#define N_WS 196608

__global__ void invres_prep(const float* __restrict__ W1, const float* __restrict__ W2,
                            const float* __restrict__ W3, unsigned short* __restrict__ wsb) {
  int idx = blockIdx.x * 256 + threadIdx.x;
  if (idx >= N_WS) return;
  int j = idx & 7;
  int lane = (idx >> 3) & 63;
  int nn = lane & 15, kn = (lane >> 4) * 8 + j;
  float val;
  if (idx < O_R2) {                // R1, KS=2
    int g = idx >> 9; int s = g & 1; int ct = g >> 1;
    val = W1[(ct * 16 + nn) * 64 + (s * 32 + kn)];
  } else if (idx < O_R3) {         // R2, KS=8
    int g = (idx - O_R2) >> 9; int s = g & 7; int ct = g >> 3;
    val = W2[(ct * 16 + nn) * 256 + (s * 32 + kn)];
  } else if (idx < O_R4) {         // R3, KS=8
    int g = (idx - O_R3) >> 9; int s = g & 7; int ct = g >> 3;
    val = W3[(ct * 16 + nn) * 256 + (s * 32 + kn)];
  } else if (idx < O_R5) {         // R4, KS=2
    int g = (idx - O_R4) >> 9; int s = g & 1; int ct = g >> 1;
    val = W3[(s * 32 + kn) * 256 + (ct * 16 + nn)];
  } else if (idx < O_R6) {         // R5, KS=8
    int g = (idx - O_R5) >> 9; int s = g & 7; int ct = g >> 3;
    val = W2[(s * 32 + kn) * 256 + (ct * 16 + nn)];
  } else {                         // R6, KS=8
    int g = (idx - O_R6) >> 9; int s = g & 7; int ct = g >> 3;
    val = W1[(s * 32 + kn) * 64 + (ct * 16 + nn)];
  }
  wsb[idx] = f2bf(val);
}

// LDS (per block, M=32):
//  PA 32x256 bf16 swz (16K): h1 then u2        PB (16K): h2 then u1
//  WB 32x64  bf16 swz (4K) : w
//  D1/D2 (16K each): elu' masks, thread-private b64 granules [wid][mc][lane]
//  LDP f32[32][4] (512B)
#define L_PB  16384
#define L_WB  32768
#define L_D1  36864
#define L_D2  53248
#define L_LDP 69632
#define L_SIZE 70144

__global__ void __launch_bounds__(512, 4)
invres_main(const float* __restrict__ y, const float* __restrict__ ldj,
            const float* __restrict__ v, const float* __restrict__ b1,
            const float* __restrict__ b2, const float* __restrict__ b3,
            const unsigned short* __restrict__ wsb, float* __restrict__ out) {
  extern __shared__ char smem[];
  char* PA = smem;
  char* PB = smem + L_PB;
  char* WB = smem + L_WB;
  char* D1 = smem + L_D1;
  char* D2 = smem + L_D2;
  float* ldp = (float*)(smem + L_LDP);

  const int tid = threadIdx.x;
  const int lane = tid & 63;
  const int wid = tid >> 6;          // 0..7
  const int l15 = lane & 15, g16 = lane >> 4;
  const int ct0 = wid * 2;           // wide: col tiles ct0, ct0+1 (32 cols)
  const int mh = wid >> 2;           // narrow: row half (16 rows)
  const int ctn = wid & 3;           // narrow: col tile (16 cols)
  const int r0 = blockIdx.x * 32;

  const bf16x8* R1 = (const bf16x8*)(wsb + O_R1);
  const bf16x8* R2 = (const bf16x8*)(wsb + O_R2);
  const bf16x8* R3 = (const bf16x8*)(wsb + O_R3);
  const bf16x8* R4 = (const bf16x8*)(wsb + O_R4);
  const bf16x8* R5 = (const bf16x8*)(wsb + O_R5);
  const bf16x8* R6 = (const bf16x8*)(wsb + O_R6);

  // mask granule byte offset (thread-private slot): [wid][mc][lane] x 8B
  auto mOff = [&](int mc) -> int { return ((wid * 4 + mc) * 64 + lane) * 8; };

  // Activation fragment (MFMA B-operand: j=row=l15, k-bundle g16) from swz LDS
  auto ldsA = [&](const char* buf, int mm, int s) -> bf16x8 {
    int row = mm * 16 + l15;
    unsigned byte = ((unsigned)(s * 64 + g16 * 16)) ^ swz(row);
    return *(const bf16x8*)(buf + row * 512 + byte);
  };
  // swapped-D epilogue store: lane holds 4 consecutive cols of row mm*16+l15 -> one b64
  auto stage64 = [&](char* buf, int mm, int cc, const float* hv) {
    int row = mm * 16 + l15;
    unsigned byte = ((unsigned)(((ct0 + cc) * 16 + g16 * 4) * 2)) ^ swz(row);
    u32x2 w; w[0] = pk2(hv[0], hv[1]); w[1] = pk2(hv[2], hv[3]);
    *(u32x2*)(buf + row * 512 + byte) = w;
  };
  // global activation fragment from y/v (row-major fp32), NT
  auto gA = [&](const float* p, int mm, int s, bool elu) -> bf16x8 {
    const float* q = p + (size_t)(r0 + mm * 16 + l15) * 64 + s * 32 + g16 * 8;
    f32x4 a = __builtin_nontemporal_load((const f32x4*)q);
    f32x4 b = __builtin_nontemporal_load((const f32x4*)(q + 4));
    float xv[8] = {a[0], a[1], a[2], a[3], b[0], b[1], b[2], b[3]};
    bf16x8 f;
#pragma unroll
    for (int i = 0; i < 8; i++) {
      float x = xv[i];
      if (elu) x = x > 0.f ? x : (__expf(x) - 1.f);
      f[i] = (short)f2bf(x);
    }
    return f;
  };

  f32x4 bv1[2], bv2[2], bv3;
#pragma unroll
  for (int cc = 0; cc < 2; cc++) {
    bv1[cc] = *(const f32x4*)(b1 + (ct0 + cc) * 16 + g16 * 4);
    bv2[cc] = *(const f32x4*)(b2 + (ct0 + cc) * 16 + g16 * 4);
  }
  bv3 = *(const f32x4*)(b3 + ctn * 16 + g16 * 4);

  unsigned d0p[2], v0p[2];
  float ldacc[4] = {0.f, 0.f, 0.f, 0.f};

  // ---------------- G1: h1 = elu(elu(y) @ W1^T + b1) -> PA ; d1 -> D1 ----------------
  {
    f32x4 acc[2][2] = {};
#pragma unroll
    for (int s = 0; s < 2; s++) {
      bf16x8 a0 = gA(y, 0, s, true);
      bf16x8 a1 = gA(y, 1, s, true);
#pragma unroll
      for (int cc = 0; cc < 2; cc++) {
        bf16x8 B = R1[((ct0 + cc) * 2 + s) * 64 + lane];
        acc[0][cc] = MFMA16(B, a0, acc[0][cc]);
        acc[1][cc] = MFMA16(B, a1, acc[1][cc]);
      }
    }
#pragma unroll
    for (int mm = 0; mm < 2; mm++)
#pragma unroll
      for (int cc = 0; cc < 2; cc++) {
        float hv[4], dv[4];
#pragma unroll
        for (int r = 0; r < 4; r++) {
          float a = acc[mm][cc][r] + bv1[cc][r];
          float e = __expf(a);
          hv[r] = a > 0.f ? a : (e - 1.f);
          dv[r] = a > 0.f ? 1.f : e;
        }
        stage64(PA, mm, cc, hv);
        u32x2 w; w[0] = pk2(dv[0], dv[1]); w[1] = pk2(dv[2], dv[3]);
        *(u32x2*)(D1 + mOff(mm * 2 + cc)) = w;
      }
  }
  __syncthreads();

  // ---------------- G2: h2 = elu(h1 @ W2^T + b2) -> PB ; d2 -> D2 ----------------
  {
    f32x4 acc[2][2] = {};
    bf16x8 a0 = ldsA(PA, 0, 0);
    bf16x8 a1 = ldsA(PA, 1, 0);
#pragma unroll 1
    for (int s = 0; s < 8; s++) {
      bf16x8 c0 = a0, c1 = a1;
      int sn = s < 7 ? s + 1 : 7;
      a0 = ldsA(PA, 0, sn);
      a1 = ldsA(PA, 1, sn);
      bf16x8 B0 = R2[(ct0 * 8 + s) * 64 + lane];
      bf16x8 B1 = R2[((ct0 + 1) * 8 + s) * 64 + lane];
      acc[0][0] = MFMA16(B0, c0, acc[0][0]);
      acc[0][1] = MFMA16(B1, c0, acc[0][1]);
      acc[1][0] = MFMA16(B0, c1, acc[1][0]);
      acc[1][1] = MFMA16(B1, c1, acc[1][1]);
    }
#pragma unroll
    for (int mm = 0; mm < 2; mm++)
#pragma unroll
      for (int cc = 0; cc < 2; cc++) {
        float hv[4], dv[4];
#pragma unroll
        for (int r = 0; r < 4; r++) {
          float a = acc[mm][cc][r] + bv2[cc][r];
          float e = __expf(a);
          hv[r] = a > 0.f ? a : (e - 1.f);
          dv[r] = a > 0.f ? 1.f : e;
        }
        stage64(PB, mm, cc, hv);
        u32x2 w; w[0] = pk2(dv[0], dv[1]); w[1] = pk2(dv[2], dv[3]);
        *(u32x2*)(D2 + mOff(mm * 2 + cc)) = w;
      }
  }
  __syncthreads();

  // ---------------- G3: z = y + h2 @ W3^T + b3 ; d0, v0 ----------------
  {
    f32x4 acc0 = {}, acc1 = {};
    bf16x8 p0 = ldsA(PB, mh, 0);
    bf16x8 p1 = ldsA(PB, mh, 1);
#pragma unroll 1
    for (int s = 0; s < 8; s += 2) {
      bf16x8 c0 = p0, c1 = p1;
      int sn = s + 2 < 8 ? s + 2 : 0;
      p0 = ldsA(PB, mh, sn);
      p1 = ldsA(PB, mh, sn + 1);
      acc0 = MFMA16(R3[(ctn * 8 + s) * 64 + lane], c0, acc0);
      acc1 = MFMA16(R3[(ctn * 8 + s + 1) * 64 + lane], c1, acc1);
    }
    int row = r0 + mh * 16 + l15;
    int col = ctn * 16 + g16 * 4;
    size_t off = (size_t)row * 64 + col;
    f32x4 yv = __builtin_nontemporal_load((const f32x4*)(y + off));
    f32x4 vv = __builtin_nontemporal_load((const f32x4*)(v + off));
    f32x4 zv;
    float d0v[4];
#pragma unroll
    for (int r = 0; r < 4; r++) {
      zv[r] = yv[r] + acc0[r] + acc1[r] + bv3[r];
      d0v[r] = yv[r] > 0.f ? 1.f : __expf(yv[r]);
    }
    __builtin_nontemporal_store(zv, (f32x4*)(out + off));
    d0p[0] = pk2(d0v[0], d0v[1]); d0p[1] = pk2(d0v[2], d0v[3]);
    v0p[0] = pk2(vv[0], vv[1]);   v0p[1] = pk2(vv[2], vv[3]);
  }

  // ---------------- G4 (k=1): u2 = (v0 @ W3) * d2 -> PA ----------------
  {
    f32x4 acc[2][2] = {};
#pragma unroll
    for (int s = 0; s < 2; s++) {
      bf16x8 a0 = gA(v, 0, s, false);
      bf16x8 a1 = gA(v, 1, s, false);
#pragma unroll
      for (int cc = 0; cc < 2; cc++) {
        bf16x8 B = R4[((ct0 + cc) * 2 + s) * 64 + lane];
        acc[0][cc] = MFMA16(B, a0, acc[0][cc]);
        acc[1][cc] = MFMA16(B, a1, acc[1][cc]);
      }
    }
#pragma unroll
    for (int mm = 0; mm < 2; mm++)
#pragma unroll
      for (int cc = 0; cc < 2; cc++) {
        u32x2 dd = *(const u32x2*)(D2 + mOff(mm * 2 + cc));
        float uv[4];
#pragma unroll
        for (int r = 0; r < 4; r++)
          uv[r] = acc[mm][cc][r] * bf2f((dd[r >> 1] >> ((r & 1) * 16)) & 0xffffu);
        stage64(PA, mm, cc, uv);
      }
  }
  __syncthreads();

  // ---------------- backward iterations ----------------
  for (int k = 1; k <= 8; ++k) {
    // G5: u1 = (u2 @ W2) * d1 -> PB
    {
      f32x4 acc[2][2] = {};
      bf16x8 a0 = ldsA(PA, 0, 0);
      bf16x8 a1 = ldsA(PA, 1, 0);
#pragma unroll 1
      for (int s = 0; s < 8; s++) {
        bf16x8 c0 = a0, c1 = a1;
        int sn = s < 7 ? s + 1 : 7;
        a0 = ldsA(PA, 0, sn);
        a1 = ldsA(PA, 1, sn);
        bf16x8 B0 = R5[(ct0 * 8 + s) * 64 + lane];
        bf16x8 B1 = R5[((ct0 + 1) * 8 + s) * 64 + lane];
        acc[0][0] = MFMA16(B0, c0, acc[0][0]);
        acc[0][1] = MFMA16(B1, c0, acc[0][1]);
        acc[1][0] = MFMA16(B0, c1, acc[1][0]);
        acc[1][1] = MFMA16(B1, c1, acc[1][1]);
      }
#pragma unroll
      for (int mm = 0; mm < 2; mm++)
#pragma unroll
        for (int cc = 0; cc < 2; cc++) {
          u32x2 dd = *(const u32x2*)(D1 + mOff(mm * 2 + cc));
          float uv[4];
#pragma unroll
          for (int r = 0; r < 4; r++)
            uv[r] = acc[mm][cc][r] * bf2f((dd[r >> 1] >> ((r & 1) * 16)) & 0xffffu);
          stage64(PB, mm, cc, uv);
        }
    }
    __syncthreads();

    // G6: w' = (u1 @ W1) * d0 ; log-det ; w' -> WB
    {
      float coef = (k & 1) ? (1.f / (float)k) : (-1.f / (float)k);
      f32x4 acc0 = {}, acc1 = {};
      bf16x8 p0 = ldsA(PB, mh, 0);
      bf16x8 p1 = ldsA(PB, mh, 1);
#pragma unroll 1
      for (int s = 0; s < 8; s += 2) {
        bf16x8 c0 = p0, c1 = p1;
        int sn = s + 2 < 8 ? s + 2 : 0;
        p0 = ldsA(PB, mh, sn);
        p1 = ldsA(PB, mh, sn + 1);
        acc0 = MFMA16(R6[(ctn * 8 + s) * 64 + lane], c0, acc0);
        acc1 = MFMA16(R6[(ctn * 8 + s + 1) * 64 + lane], c1, acc1);
      }
      float wv[4];
#pragma unroll
      for (int r = 0; r < 4; r++) {
        wv[r] = (acc0[r] + acc1[r]) * bf2f((d0p[r >> 1] >> ((r & 1) * 16)) & 0xffffu);
        ldacc[r] += coef * wv[r] * bf2f((v0p[r >> 1] >> ((r & 1) * 16)) & 0xffffu);
      }
      if (k < 8) {
        int row = mh * 16 + l15;
        unsigned byte = ((unsigned)((ctn * 16 + g16 * 4) * 2)) ^ swz(row);
        u32x2 w; w[0] = pk2(wv[0], wv[1]); w[1] = pk2(wv[2], wv[3]);
        *(u32x2*)(WB + row * 128 + byte) = w;
      }
    }
    if (k < 8) {
      __syncthreads();
      // G4': u2 = (w' @ W3) * d2 -> PA
      f32x4 acc[2][2] = {};
#pragma unroll
      for (int s = 0; s < 2; s++) {
        bf16x8 a0, a1;
#pragma unroll
        for (int mm = 0; mm < 2; mm++) {
          int row = mm * 16 + l15;
          unsigned byte = ((unsigned)(s * 64 + g16 * 16)) ^ swz(row);
          bf16x8 a = *(const bf16x8*)(WB + row * 128 + byte);
          if (mm == 0) a0 = a; else a1 = a;
        }
#pragma unroll
        for (int cc = 0; cc < 2; cc++) {
          bf16x8 B = R4[((ct0 + cc) * 2 + s) * 64 + lane];
          acc[0][cc] = MFMA16(B, a0, acc[0][cc]);
          acc[1][cc] = MFMA16(B, a1, acc[1][cc]);
        }
      }
#pragma unroll
      for (int mm = 0; mm < 2; mm++)
#pragma unroll
        for (int cc = 0; cc < 2; cc++) {
          u32x2 dd = *(const u32x2*)(D2 + mOff(mm * 2 + cc));
          float uv[4];
#pragma unroll
          for (int r = 0; r < 4; r++)
            uv[r] = acc[mm][cc][r] * bf2f((dd[r >> 1] >> ((r & 1) * 16)) & 0xffffu);
          stage64(PA, mm, cc, uv);
        }
      __syncthreads();
    }
  }

  // ---------------- log-det epilogue ----------------
  {
    float s = ldacc[0] + ldacc[1] + ldacc[2] + ldacc[3];
    s += __shfl_xor(s, 16);
    s += __shfl_xor(s, 32);
    if (g16 == 0) ldp[(mh * 16 + l15) * 4 + ctn] = s;
  }
  __syncthreads();
  if (tid < 32) {
    float s = ldp[tid * 4] + ldp[tid * 4 + 1] + ldp[tid * 4 + 2] + ldp[tid * 4 + 3];
    int gb = r0 + tid;
    __builtin_nontemporal_store(ldj[gb] + s, out + (size_t)BN * 64 + gb);
  }
}

extern "C" void kernel_launch(void* const* d_in, const int* in_sizes, int n_in,
                              void* d_out, int out_size, void* d_ws, size_t ws_size,
                              hipStream_t stream) {
  const float* y   = (const float*)d_in[0];
  const float* ldj = (const float*)d_in[1];
  const float* v   = (const float*)d_in[2];
  const float* W1  = (const float*)d_in[3];
  const float* b1  = (const float*)d_in[4];
  const float* W2  = (const float*)d_in[5];
  const float* b2  = (const float*)d_in[6];
  const float* W3  = (const float*)d_in[7];
  const float* b3  = (const float*)d_in[8];
  unsigned short* wsb = (unsigned short*)d_ws;
  float* out = (float*)d_out;

  (void)hipFuncSetAttribute(reinterpret_cast<const void*>(&invres_main),
                            hipFuncAttributeMaxDynamicSharedMemorySize, L_SIZE);

  invres_prep<<<N_WS / 256, 256, 0, stream>>>(W1, W2, W3, wsb);
  invres_main<<<BN / 32, 512, L_SIZE, stream>>>(y, ldj, v, b1, b2, b3, wsb, out);
}

// Round 17
// 781.595 us; speedup vs baseline: 2.5624x; 1.0317x over previous
//
#include <hip/hip_runtime.h>

#define BN 262144

typedef short bf16x8 __attribute__((ext_vector_type(8)));
typedef float f32x4 __attribute__((ext_vector_type(4)));
typedef unsigned int u32x2 __attribute__((ext_vector_type(2)));

#define MFMA16(a,b,c) __builtin_amdgcn_mfma_f32_16x16x32_bf16((a),(b),(c),0,0,0)

__device__ __forceinline__ unsigned short f2bf(float f) {
  union { float f; unsigned int u; } x; x.f = f;
  unsigned int u = x.u + 0x7fffu + ((x.u >> 16) & 1u);
  return (unsigned short)(u >> 16);
}
__device__ __forceinline__ float bf2f(unsigned int h) {
  union { unsigned int u; float f; } x; x.u = h << 16;
  return x.f;
}
// pack two f32 -> (bf16_lo | bf16_hi<<16), truncating (3 VALU ops)
__device__ __forceinline__ unsigned pk2(float lo, float hi) {
  union { float f; unsigned int u; } a, b; a.f = lo; b.f = hi;
  return (a.u >> 16) | (b.u & 0xffff0000u);
}
__device__ __forceinline__ unsigned swz(int row) {
  return (((unsigned)(row & 7)) << 4) ^ (((unsigned)(row & 8)) << 2);
}

// All weight arrays in 16x16x32 fragment layout (ushort units); used as the
// MFMA *A*-operand (operand-swapped scheme): i=n=ct*16+(lane&15), k=s*32+(lane>>4)*8+j
#define O_R1 0        // W1^T: [k][n]=W1[n*64+k]   K=64  N=256 KS=2
#define O_R2 16384    // W2^T: [k][n]=W2[n*256+k]  K=256 N=256 KS=8
#define O_R3 81920    // W3^T: [k][n]=W3[n*256+k]  K=256 N=64  KS=8
#define O_R4 98304    // W3  : [k][n]=W3[k*256+n]  K=64  N=256 KS=2
#define O_R5 114688   // W2  : [k][n]=W2[k*256+n]  K=256 N=256 KS=8
#define O_R6 180224   // W1  : [k][n]=W1[k*64+n]   K=256 N=64  KS=8
#define N_WS 196608

__global__ void invres_prep(const float* __restrict__ W1, const float* __restrict__ W2,
                            const float* __restrict__ W3, unsigned short* __restrict__ wsb) {
  int idx = blockIdx.x * 256 + threadIdx.x;
  if (idx >= N_WS) return;
  int j = idx & 7;
  int lane = (idx >> 3) & 63;
  int nn = lane & 15, kn = (lane >> 4) * 8 + j;
  float val;
  if (idx < O_R2) {                // R1, KS=2
    int g = idx >> 9; int s = g & 1; int ct = g >> 1;
    val = W1[(ct * 16 + nn) * 64 + (s * 32 + kn)];
  } else if (idx < O_R3) {         // R2, KS=8
    int g = (idx - O_R2) >> 9; int s = g & 7; int ct = g >> 3;
    val = W2[(ct * 16 + nn) * 256 + (s * 32 + kn)];
  } else if (idx < O_R4) {         // R3, KS=8
    int g = (idx - O_R3) >> 9; int s = g & 7; int ct = g >> 3;
    val = W3[(ct * 16 + nn) * 256 + (s * 32 + kn)];
  } else if (idx < O_R5) {         // R4, KS=2
    int g = (idx - O_R4) >> 9; int s = g & 1; int ct = g >> 1;
    val = W3[(s * 32 + kn) * 256 + (ct * 16 + nn)];
  } else if (idx < O_R6) {         // R5, KS=8
    int g = (idx - O_R5) >> 9; int s = g & 7; int ct = g >> 3;
    val = W2[(s * 32 + kn) * 256 + (ct * 16 + nn)];
  } else {                         // R6, KS=8
    int g = (idx - O_R6) >> 9; int s = g & 7; int ct = g >> 3;
    val = W1[(s * 32 + kn) * 64 + (ct * 16 + nn)];
  }
  wsb[idx] = f2bf(val);
}

// LDS (per block, M=32), SINGLE staging buffer P time-shared (h1->h2->u2/u1):
//  P  32x256 bf16 swz (16K)
//  WB 32x64  bf16 swz (4K)
//  D1/D2 (16K each): elu' masks, thread-private b64 granules [wid][mc][lane]
//  LDP f32[32][4] (512B)                                total 52.5K -> 3 blocks/CU
#define L_WB  16384
#define L_D1  20480
#define L_D2  36864
#define L_LDP 53248
#define L_SIZE 53760

__global__ void __launch_bounds__(512, 6)
invres_main(const float* __restrict__ y, const float* __restrict__ ldj,
            const float* __restrict__ v, const float* __restrict__ b1,
            const float* __restrict__ b2, const float* __restrict__ b3,
            const unsigned short* __restrict__ wsb, float* __restrict__ out) {
  extern __shared__ char smem[];
  char* P  = smem;
  char* WB = smem + L_WB;
  char* D1 = smem + L_D1;
  char* D2 = smem + L_D2;
  float* ldp = (float*)(smem + L_LDP);

  const int tid = threadIdx.x;
  const int lane = tid & 63;
  const int wid = tid >> 6;          // 0..7
  const int l15 = lane & 15, g16 = lane >> 4;
  const int ct0 = wid * 2;           // wide: col tiles ct0, ct0+1 (32 cols)
  const int mh = wid >> 2;           // narrow: row half (16 rows)
  const int ctn = wid & 3;           // narrow: col tile (16 cols)
  const int r0 = blockIdx.x * 32;

  const bf16x8* R1 = (const bf16x8*)(wsb + O_R1);
  const bf16x8* R2 = (const bf16x8*)(wsb + O_R2);
  const bf16x8* R3 = (const bf16x8*)(wsb + O_R3);
  const bf16x8* R4 = (const bf16x8*)(wsb + O_R4);
  const bf16x8* R5 = (const bf16x8*)(wsb + O_R5);
  const bf16x8* R6 = (const bf16x8*)(wsb + O_R6);

  // mask granule byte offset (thread-private slot): [wid][mc][lane] x 8B
  auto mOff = [&](int mc) -> int { return ((wid * 4 + mc) * 64 + lane) * 8; };

  // Activation fragment (MFMA B-operand: j=row=l15, k-bundle g16) from swz LDS
  auto ldsA = [&](const char* buf, int mm, int s) -> bf16x8 {
    int row = mm * 16 + l15;
    unsigned byte = ((unsigned)(s * 64 + g16 * 16)) ^ swz(row);
    return *(const bf16x8*)(buf + row * 512 + byte);
  };
  // swapped-D epilogue store: lane holds 4 consecutive cols of row mm*16+l15 -> one b64
  auto stage64 = [&](char* buf, int mm, int cc, const float* hv) {
    int row = mm * 16 + l15;
    unsigned byte = ((unsigned)(((ct0 + cc) * 16 + g16 * 4) * 2)) ^ swz(row);
    u32x2 w; w[0] = pk2(hv[0], hv[1]); w[1] = pk2(hv[2], hv[3]);
    *(u32x2*)(buf + row * 512 + byte) = w;
  };
  // global activation fragment from y/v (row-major fp32), NT
  auto gA = [&](const float* p, int mm, int s, bool elu) -> bf16x8 {
    const float* q = p + (size_t)(r0 + mm * 16 + l15) * 64 + s * 32 + g16 * 8;
    f32x4 a = __builtin_nontemporal_load((const f32x4*)q);
    f32x4 b = __builtin_nontemporal_load((const f32x4*)(q + 4));
    float xv[8] = {a[0], a[1], a[2], a[3], b[0], b[1], b[2], b[3]};
    bf16x8 f;
#pragma unroll
    for (int i = 0; i < 8; i++) {
      float x = xv[i];
      if (elu) x = x > 0.f ? x : (__expf(x) - 1.f);
      f[i] = (short)f2bf(x);
    }
    return f;
  };

  unsigned d0p[2], v0p[2];
  float ldacc[4] = {0.f, 0.f, 0.f, 0.f};

  // ---------------- G1: h1 = elu(elu(y) @ W1^T + b1) -> P ; d1 -> D1 ----------------
  {
    f32x4 bv1[2];
#pragma unroll
    for (int cc = 0; cc < 2; cc++) bv1[cc] = *(const f32x4*)(b1 + (ct0 + cc) * 16 + g16 * 4);
    f32x4 acc[2][2] = {};
#pragma unroll
    for (int s = 0; s < 2; s++) {
      bf16x8 a0 = gA(y, 0, s, true);
      bf16x8 a1 = gA(y, 1, s, true);
#pragma unroll
      for (int cc = 0; cc < 2; cc++) {
        bf16x8 B = R1[((ct0 + cc) * 2 + s) * 64 + lane];
        acc[0][cc] = MFMA16(B, a0, acc[0][cc]);
        acc[1][cc] = MFMA16(B, a1, acc[1][cc]);
      }
    }
#pragma unroll
    for (int mm = 0; mm < 2; mm++)
#pragma unroll
      for (int cc = 0; cc < 2; cc++) {
        float hv[4], dv[4];
#pragma unroll
        for (int r = 0; r < 4; r++) {
          float a = acc[mm][cc][r] + bv1[cc][r];
          float e = __expf(a);
          hv[r] = a > 0.f ? a : (e - 1.f);
          dv[r] = a > 0.f ? 1.f : e;
        }
        stage64(P, mm, cc, hv);
        u32x2 w; w[0] = pk2(dv[0], dv[1]); w[1] = pk2(dv[2], dv[3]);
        *(u32x2*)(D1 + mOff(mm * 2 + cc)) = w;
      }
  }
  __syncthreads();

  // ---------------- G2: h2 = elu(h1 @ W2^T + b2) -> P (split) ; d2 -> D2 ----------------
  {
    f32x4 acc[2][2] = {};
#pragma unroll 1
    for (int s = 0; s < 8; s++) {
      bf16x8 a0 = ldsA(P, 0, s);
      bf16x8 a1 = ldsA(P, 1, s);
      bf16x8 B0 = R2[(ct0 * 8 + s) * 64 + lane];
      bf16x8 B1 = R2[((ct0 + 1) * 8 + s) * 64 + lane];
      acc[0][0] = MFMA16(B0, a0, acc[0][0]);
      acc[0][1] = MFMA16(B1, a0, acc[0][1]);
      acc[1][0] = MFMA16(B0, a1, acc[1][0]);
      acc[1][1] = MFMA16(B1, a1, acc[1][1]);
    }
    __syncthreads();   // all h1 reads done before overwrite
    f32x4 bv2[2];
#pragma unroll
    for (int cc = 0; cc < 2; cc++) bv2[cc] = *(const f32x4*)(b2 + (ct0 + cc) * 16 + g16 * 4);
#pragma unroll
    for (int mm = 0; mm < 2; mm++)
#pragma unroll
      for (int cc = 0; cc < 2; cc++) {
        float hv[4], dv[4];
#pragma unroll
        for (int r = 0; r < 4; r++) {
          float a = acc[mm][cc][r] + bv2[cc][r];
          float e = __expf(a);
          hv[r] = a > 0.f ? a : (e - 1.f);
          dv[r] = a > 0.f ? 1.f : e;
        }
        stage64(P, mm, cc, hv);
        u32x2 w; w[0] = pk2(dv[0], dv[1]); w[1] = pk2(dv[2], dv[3]);
        *(u32x2*)(D2 + mOff(mm * 2 + cc)) = w;
      }
  }
  __syncthreads();

  // ---------------- G3: z = y + h2 @ W3^T + b3 ; d0, v0 ----------------
  {
    f32x4 acc0 = {}, acc1 = {};
#pragma unroll 1
    for (int s = 0; s < 8; s += 2) {
      acc0 = MFMA16(R3[(ctn * 8 + s) * 64 + lane], ldsA(P, mh, s), acc0);
      acc1 = MFMA16(R3[(ctn * 8 + s + 1) * 64 + lane], ldsA(P, mh, s + 1), acc1);
    }
    f32x4 bv3 = *(const f32x4*)(b3 + ctn * 16 + g16 * 4);
    int row = r0 + mh * 16 + l15;
    int col = ctn * 16 + g16 * 4;
    size_t off = (size_t)row * 64 + col;
    f32x4 yv = __builtin_nontemporal_load((const f32x4*)(y + off));
    f32x4 vv = __builtin_nontemporal_load((const f32x4*)(v + off));
    f32x4 zv;
    float d0v[4];
#pragma unroll
    for (int r = 0; r < 4; r++) {
      zv[r] = yv[r] + acc0[r] + acc1[r] + bv3[r];
      d0v[r] = yv[r] > 0.f ? 1.f : __expf(yv[r]);
    }
    __builtin_nontemporal_store(zv, (f32x4*)(out + off));
    d0p[0] = pk2(d0v[0], d0v[1]); d0p[1] = pk2(d0v[2], d0v[3]);
    v0p[0] = pk2(vv[0], vv[1]);   v0p[1] = pk2(vv[2], vv[3]);
  }
  __syncthreads();   // h2 reads done before u2 overwrites P

  // ---------------- G4 (k=1): u2 = (v0 @ W3) * d2 -> P ----------------
  {
    f32x4 acc[2][2] = {};
#pragma unroll
    for (int s = 0; s < 2; s++) {
      bf16x8 a0 = gA(v, 0, s, false);
      bf16x8 a1 = gA(v, 1, s, false);
#pragma unroll
      for (int cc = 0; cc < 2; cc++) {
        bf16x8 B = R4[((ct0 + cc) * 2 + s) * 64 + lane];
        acc[0][cc] = MFMA16(B, a0, acc[0][cc]);
        acc[1][cc] = MFMA16(B, a1, acc[1][cc]);
      }
    }
#pragma unroll
    for (int mm = 0; mm < 2; mm++)
#pragma unroll
      for (int cc = 0; cc < 2; cc++) {
        u32x2 dd = *(const u32x2*)(D2 + mOff(mm * 2 + cc));
        float uv[4];
#pragma unroll
        for (int r = 0; r < 4; r++)
          uv[r] = acc[mm][cc][r] * bf2f((dd[r >> 1] >> ((r & 1) * 16)) & 0xffffu);
        stage64(P, mm, cc, uv);
      }
  }
  __syncthreads();

  // ---------------- backward iterations ----------------
  for (int k = 1; k <= 8; ++k) {
    // G5: u1 = (u2 @ W2) * d1 -> P (split read|write)
    {
      f32x4 acc[2][2] = {};
#pragma unroll 1
      for (int s = 0; s < 8; s++) {
        bf16x8 a0 = ldsA(P, 0, s);
        bf16x8 a1 = ldsA(P, 1, s);
        bf16x8 B0 = R5[(ct0 * 8 + s) * 64 + lane];
        bf16x8 B1 = R5[((ct0 + 1) * 8 + s) * 64 + lane];
        acc[0][0] = MFMA16(B0, a0, acc[0][0]);
        acc[0][1] = MFMA16(B1, a0, acc[0][1]);
        acc[1][0] = MFMA16(B0, a1, acc[1][0]);
        acc[1][1] = MFMA16(B1, a1, acc[1][1]);
      }
      __syncthreads();   // all u2 reads done
#pragma unroll
      for (int mm = 0; mm < 2; mm++)
#pragma unroll
        for (int cc = 0; cc < 2; cc++) {
          u32x2 dd = *(const u32x2*)(D1 + mOff(mm * 2 + cc));
          float uv[4];
#pragma unroll
          for (int r = 0; r < 4; r++)
            uv[r] = acc[mm][cc][r] * bf2f((dd[r >> 1] >> ((r & 1) * 16)) & 0xffffu);
          stage64(P, mm, cc, uv);
        }
    }
    __syncthreads();

    // G6: w' = (u1 @ W1) * d0 ; log-det ; w' -> WB
    {
      float coef = (k & 1) ? (1.f / (float)k) : (-1.f / (float)k);
      f32x4 acc0 = {}, acc1 = {};
#pragma unroll 1
      for (int s = 0; s < 8; s += 2) {
        acc0 = MFMA16(R6[(ctn * 8 + s) * 64 + lane], ldsA(P, mh, s), acc0);
        acc1 = MFMA16(R6[(ctn * 8 + s + 1) * 64 + lane], ldsA(P, mh, s + 1), acc1);
      }
      float wv[4];
#pragma unroll
      for (int r = 0; r < 4; r++) {
        wv[r] = (acc0[r] + acc1[r]) * bf2f((d0p[r >> 1] >> ((r & 1) * 16)) & 0xffffu);
        ldacc[r] += coef * wv[r] * bf2f((v0p[r >> 1] >> ((r & 1) * 16)) & 0xffffu);
      }
      if (k < 8) {
        int row = mh * 16 + l15;
        unsigned byte = ((unsigned)((ctn * 16 + g16 * 4) * 2)) ^ swz(row);
        u32x2 w; w[0] = pk2(wv[0], wv[1]); w[1] = pk2(wv[2], wv[3]);
        *(u32x2*)(WB + row * 128 + byte) = w;
      }
    }
    if (k < 8) {
      __syncthreads();   // WB written, u1 reads done
      // G4': u2 = (w' @ W3) * d2 -> P
      f32x4 acc[2][2] = {};
#pragma unroll
      for (int s = 0; s < 2; s++) {
        bf16x8 a0, a1;
#pragma unroll
        for (int mm = 0; mm < 2; mm++) {
          int row = mm * 16 + l15;
          unsigned byte = ((unsigned)(s * 64 + g16 * 16)) ^ swz(row);
          bf16x8 a = *(const bf16x8*)(WB + row * 128 + byte);
          if (mm == 0) a0 = a; else a1 = a;
        }
#pragma unroll
        for (int cc = 0; cc < 2; cc++) {
          bf16x8 B = R4[((ct0 + cc) * 2 + s) * 64 + lane];
          acc[0][cc] = MFMA16(B, a0, acc[0][cc]);
          acc[1][cc] = MFMA16(B, a1, acc[1][cc]);
        }
      }
#pragma unroll
      for (int mm = 0; mm < 2; mm++)
#pragma unroll
        for (int cc = 0; cc < 2; cc++) {
          u32x2 dd = *(const u32x2*)(D2 + mOff(mm * 2 + cc));
          float uv[4];
#pragma unroll
          for (int r = 0; r < 4; r++)
            uv[r] = acc[mm][cc][r] * bf2f((dd[r >> 1] >> ((r & 1) * 16)) & 0xffffu);
          stage64(P, mm, cc, uv);
        }
      __syncthreads();
    }
  }

  // ---------------- log-det epilogue ----------------
  {
    float s = ldacc[0] + ldacc[1] + ldacc[2] + ldacc[3];
    s += __shfl_xor(s, 16);
    s += __shfl_xor(s, 32);
    if (g16 == 0) ldp[(mh * 16 + l15) * 4 + ctn] = s;
  }
  __syncthreads();
  if (tid < 32) {
    float s = ldp[tid * 4] + ldp[tid * 4 + 1] + ldp[tid * 4 + 2] + ldp[tid * 4 + 3];
    int gb = r0 + tid;
    __builtin_nontemporal_store(ldj[gb] + s, out + (size_t)BN * 64 + gb);
  }
}

extern "C" void kernel_launch(void* const* d_in, const int* in_sizes, int n_in,
                              void* d_out, int out_size, void* d_ws, size_t ws_size,
                              hipStream_t stream) {
  const float* y   = (const float*)d_in[0];
  const float* ldj = (const float*)d_in[1];
  const float* v   = (const float*)d_in[2];
  const float* W1  = (const float*)d_in[3];
  const float* b1  = (const float*)d_in[4];
  const float* W2  = (const float*)d_in[5];
  const float* b2  = (const float*)d_in[6];
  const float* W3  = (const float*)d_in[7];
  const float* b3  = (const float*)d_in[8];
  unsigned short* wsb = (unsigned short*)d_ws;
  float* out = (float*)d_out;

  (void)hipFuncSetAttribute(reinterpret_cast<const void*>(&invres_main),
                            hipFuncAttributeMaxDynamicSharedMemorySize, L_SIZE);

  invres_prep<<<N_WS / 256, 256, 0, stream>>>(W1, W2, W3, wsb);
  invres_main<<<BN / 32, 512, L_SIZE, stream>>>(y, ldj, v, b1, b2, b3, wsb, out);
}